// Round 7
// baseline (985.130 us; speedup 1.0000x reference)
//
#include <hip/hip_runtime.h>
#include <hip/hip_bf16.h>

#define E_ 128
#define NSAMP 2048

typedef __attribute__((ext_vector_type(8))) short short8;
typedef __attribute__((ext_vector_type(4))) float floatx4;

__device__ __forceinline__ ushort f2b(float f) {
    union { __hip_bfloat16 h; ushort u; } cv;
    cv.h = __float2bfloat16(f);
    return cv.u;
}

__device__ __forceinline__ void gload_lds16(const ushort* g, ushort* l) {
    __builtin_amdgcn_global_load_lds(
        (const __attribute__((address_space(1))) void*)g,
        (__attribute__((address_space(3))) void*)l, 16, 0, 0);
}

// -------------------- h = ReLU(ids @ l1W^T + l1b), fp32 --------------------
__global__ void hyper_h(const float* __restrict__ input, const float* __restrict__ l1W,
                        const float* __restrict__ l1b, float* __restrict__ h)
{
    int b = blockIdx.x / 5;
    int o = (blockIdx.x % 5) * 256 + threadIdx.x;
    const float* ids = input + (size_t)b * 192 + 176;
    const float* w = l1W + (size_t)o * 16;
    float a = l1b[o];
#pragma unroll
    for (int i = 0; i < 16; i += 4) {
        float4 wv = *(const float4*)(w + i);
        a += ids[i] * wv.x + ids[i + 1] * wv.y + ids[i + 2] * wv.z + ids[i + 3] * wv.w;
    }
    h[(size_t)b * 1280 + o] = fmaxf(a, 0.f);
}

// -------------------- xT0[s][b] = input[b][s]  (s < 176), fp32 --------------------
__global__ void x0_t(const float* __restrict__ input, float* __restrict__ xT0)
{
    int idx = blockIdx.x * 256 + threadIdx.x;   // < 176*2048
    int s = idx >> 11, b = idx & 2047;
    xT0[idx] = input[(size_t)b * 192 + s];
}

// ---------- fused per-layer weight prep: wW -> bf16, plus 3 virtual B-slices ----------
__global__ void cvt_layer(const float* __restrict__ wW, const float* __restrict__ wb,
                          const float* __restrict__ bW, ushort* __restrict__ dst,
                          int S, int M)
{
    int i = (blockIdx.x * 256 + threadIdx.x) * 8;       // 8 dst elements per thread
    const int nW = S * M * E_;
    union { ushort o[8]; uint4 v; } u;
    if (i < nW) {
        float4 a = *(const float4*)(wW + i);
        float4 b = *(const float4*)(wW + i + 4);
        u.o[0] = f2b(a.x); u.o[1] = f2b(a.y); u.o[2] = f2b(a.z); u.o[3] = f2b(a.w);
        u.o[4] = f2b(b.x); u.o[5] = f2b(b.y); u.o[6] = f2b(b.z); u.o[7] = f2b(b.w);
    } else {
        int rem = i - nW;                   // < 3*M*E_
        int slice = rem / (M * E_);
        int r2 = rem - slice * (M * E_);
        int m = r2 >> 7, e = r2 & 127;      // E_ = 128
        if (slice == 0) {
            const float* src = bW + (size_t)m * E_ + e;
            float4 a = *(const float4*)(src);
            float4 b = *(const float4*)(src + 4);
            u.o[0] = f2b(a.x); u.o[1] = f2b(a.y); u.o[2] = f2b(a.z); u.o[3] = f2b(a.w);
            u.o[4] = f2b(b.x); u.o[5] = f2b(b.y); u.o[6] = f2b(b.z); u.o[7] = f2b(b.w);
        } else {
#pragma unroll
            for (int jj = 0; jj < 8; ++jj) {
                int s = (slice - 1) * 128 + e + jj;
                u.o[jj] = (s < S) ? f2b(wb[(size_t)s * M + m]) : (ushort)0;
            }
        }
    }
    *(uint4*)(dst + i) = u.v;
}

// ==================== big-layer GEMM (M=256): BM=64, 1024 blocks, 4 blocks/CU ====================
// 256 threads (4 waves, 2x2): wave owns 32 rows x 64 cols of a 64x128 tile.
// Same proven inner math as the 65us rounds (reg-A from hreg, zero-conflict XOR swizzle,
// counted vmcnt, raw barriers). Occupancy lever: grid 1024 -> with LDS 36.3KB (ring-2 x 16KB
// + xs 4.3KB) the HW fits 4 blocks/CU = 16 waves/CU = 4 waves/SIMD (2x the 65us rounds).
// Ring-2 needs 2 barriers/phase (refill target is the buffer just read) - r3 vs r4 showed
// barrier count is neutral. launch_bounds(256,2): the only empirically-safe cap (104-112 VGPR).
__global__ __launch_bounds__(256, 2) void gemm_big(
    const ushort* __restrict__ wWb, const float* __restrict__ h,
    const float* __restrict__ xT, float* __restrict__ partial,
    int S, int iw, int ksplit, int btiles, int ntiles)
{
    __shared__ __align__(16) ushort Bs[2][128 * 64];   // ring-2, 16KB each (BK=64)
    __shared__ __align__(16) float xs[17 * 64];

    const int tid = threadIdx.x;
    // XCD-aware decode: combo (nt,ks) pinned to one XCD, its 32 bt-blocks contiguous there.
    const int bid = blockIdx.x;
    const int xcd = bid & 7;
    const int jj_ = bid >> 3;
    const int combo = xcd + 8 * (jj_ / btiles);
    const int bt = jj_ % btiles;
    const int nt = combo % ntiles;
    const int ks = combo / ntiles;
    const int b0 = bt * 64;
    const int m0 = nt * 128;
    const int total_s = S + 3;
    const int base = total_s / ksplit;
    const int rem = total_s - base * ksplit;
    const int s0 = ks * base + min(ks, rem);
    const int s1v = s0 + base + (ks < rem ? 1 : 0);
    const int sE = min(s1v, S);     // main loop covers [s0, sE)
    const int ns = sE - s0;
    const int T = 2 * ns;           // BK=64 phases

    const int lane = tid & 63;
    const int wave = tid >> 6;      // 0..3
    const int quad = lane >> 4;
    const int lr = lane & 15;
    const int wm0 = (wave >> 1) * 32;   // wave rows: 32 (of 64)
    const int wn0 = (wave & 1) * 64;    // wave cols: 64 (of 128)

    const int brow = lane >> 3;         // B-DMA local row (0..7)
    const int bgg = (lane & 7) ^ brow;  // global e-group for this lane's slot

    // h fragments: hreg[i][P][k2][j] = h[b0+wm0+i*16+lr][iw*128 + P*64 + k2*32 + quad*8 + j]
    float hreg[2][2][2][8];
#pragma unroll
    for (int i = 0; i < 2; ++i)
#pragma unroll
        for (int p = 0; p < 2; ++p)
#pragma unroll
            for (int k2 = 0; k2 < 2; ++k2) {
                const float* src = h + (size_t)(b0 + wm0 + i * 16 + lr) * 1280
                                     + (size_t)iw * E_ + p * 64 + k2 * 32 + quad * 8;
                float4 v0 = *(const float4*)(src);
                float4 v1 = *(const float4*)(src + 4);
                hreg[i][p][k2][0] = v0.x; hreg[i][p][k2][1] = v0.y;
                hreg[i][p][k2][2] = v0.z; hreg[i][p][k2][3] = v0.w;
                hreg[i][p][k2][4] = v1.x; hreg[i][p][k2][5] = v1.y;
                hreg[i][p][k2][6] = v1.z; hreg[i][p][k2][7] = v1.w;
            }

    // stage x-slice: xs[si][b_local], 64 rows per block
    for (int idx = tid; idx < ns * 64; idx += 256) {
        int j = idx >> 6, bb2 = idx & 63;
        xs[idx] = xT[(size_t)(s0 + j) * NSAMP + b0 + bb2];
    }

    floatx4 acc[2][4];
#pragma unroll
    for (int i = 0; i < 2; ++i)
#pragma unroll
        for (int j = 0; j < 4; ++j)
            acc[i][j] = (floatx4){0.f, 0.f, 0.f, 0.f};

    // BK=64 phase DMA: 4 gload_lds per wave (4 waves x 32 rows = 128 B-rows)
    auto dmaP = [&](int s, int p, ushort* buf) {
#pragma unroll
        for (int rnd = 0; rnd < 4; ++rnd) {
            int rloc = wave * 32 + rnd * 8;
            const ushort* gp = wWb + ((size_t)s * 256 + m0 + rloc + brow) * E_ + p * 64 + bgg * 8;
            gload_lds16(gp, buf + (size_t)rloc * 64 + lane * 8);
        }
    };

    // prologue: drain hreg/xs loads, then 2 phases of DMA in flight (8 loads/wave)
    __builtin_amdgcn_sched_barrier(0);
    __syncthreads();
    __builtin_amdgcn_sched_barrier(0);
    if (T > 0) dmaP(s0, 0, Bs[0]);
    if (T > 1) dmaP(s0, 1, Bs[1]);

    for (int t = 0; t < T; ++t) {
        const int si = t >> 1, P = t & 1;
        if (t + 1 < T) { asm volatile("s_waitcnt vmcnt(4)" ::: "memory"); }
        else           { asm volatile("s_waitcnt vmcnt(0)" ::: "memory"); }
        __builtin_amdgcn_sched_barrier(0);
        __builtin_amdgcn_s_barrier();          // barrier1: phase t staged for all waves
        __builtin_amdgcn_sched_barrier(0);

        const float xr0 = xs[si * 64 + wm0 + lr];
        const float xr1 = xs[si * 64 + wm0 + 16 + lr];
        const ushort* bcur = Bs[t & 1];
        __builtin_amdgcn_s_setprio(1);
#pragma unroll
        for (int k2 = 0; k2 < 2; ++k2) {
            const int swz = ((k2 * 4 + quad) ^ (lr & 7)) * 8;
            short8 bfr[4];
#pragma unroll
            for (int j = 0; j < 4; ++j)
                bfr[j] = *(const short8*)&bcur[(size_t)(wn0 + j * 16 + lr) * 64 + swz];
            short8 a0, a1;
#pragma unroll
            for (int jj = 0; jj < 8; ++jj) {
                a0[jj] = (short)f2b(xr0 * hreg[0][P][k2][jj]);
                a1[jj] = (short)f2b(xr1 * hreg[1][P][k2][jj]);
            }
#pragma unroll
            for (int j = 0; j < 4; ++j) {
                acc[0][j] = __builtin_amdgcn_mfma_f32_16x16x32_bf16(a0, bfr[j], acc[0][j], 0, 0, 0);
                acc[1][j] = __builtin_amdgcn_mfma_f32_16x16x32_bf16(a1, bfr[j], acc[1][j], 0, 0, 0);
            }
        }
        __builtin_amdgcn_s_setprio(0);
        __builtin_amdgcn_sched_barrier(0);
        __builtin_amdgcn_s_barrier();          // barrier2: all waves done reading Bs[t&1]
        __builtin_amdgcn_sched_barrier(0);

        if (t + 2 < T) dmaP(s0 + ((t + 2) >> 1), (t + 2) & 1, Bs[t & 1]);   // WAR-safe refill
    }

    // ---- virtual slices s in [S, s1v): non-pipelined (only last-ks blocks) ----
    for (int s = sE; s < s1v; ++s) {
        for (int p = 0; p < 2; ++p) {
            __syncthreads();            // full drain; previous reads complete
            dmaP(s, p, Bs[0]);
            short8 af[2][2];            // [k2][i]
            if (s == S) {
#pragma unroll
                for (int k2 = 0; k2 < 2; ++k2)
#pragma unroll
                    for (int i = 0; i < 2; ++i) {
                        const float* src = h + (size_t)(b0 + wm0 + i * 16 + lr) * 1280
                                             + (size_t)(iw + 1) * E_ + p * 64 + k2 * 32 + quad * 8;
                        float4 v0 = *(const float4*)(src);
                        float4 v1 = *(const float4*)(src + 4);
                        af[k2][i][0] = (short)f2b(v0.x); af[k2][i][1] = (short)f2b(v0.y);
                        af[k2][i][2] = (short)f2b(v0.z); af[k2][i][3] = (short)f2b(v0.w);
                        af[k2][i][4] = (short)f2b(v1.x); af[k2][i][5] = (short)f2b(v1.y);
                        af[k2][i][6] = (short)f2b(v1.z); af[k2][i][7] = (short)f2b(v1.w);
                    }
            } else {
                const int jbase = (s - S - 1) * 128 + p * 64;
#pragma unroll
                for (int k2 = 0; k2 < 2; ++k2)
#pragma unroll
                    for (int i = 0; i < 2; ++i) {
                        const int b = b0 + wm0 + i * 16 + lr;
#pragma unroll
                        for (int jj = 0; jj < 8; ++jj) {
                            const int sp = jbase + k2 * 32 + quad * 8 + jj;
                            af[k2][i][jj] = (sp < S) ? (short)f2b(xT[(size_t)sp * NSAMP + b]) : (short)0;
                        }
                    }
            }
            __syncthreads();            // DMA + af loads drained
#pragma unroll
            for (int k2 = 0; k2 < 2; ++k2) {
                const int swz = ((k2 * 4 + quad) ^ (lr & 7)) * 8;
                short8 bfr[4];
#pragma unroll
                for (int j = 0; j < 4; ++j)
                    bfr[j] = *(const short8*)&Bs[0][(size_t)(wn0 + j * 16 + lr) * 64 + swz];
#pragma unroll
                for (int j = 0; j < 4; ++j) {
                    acc[0][j] = __builtin_amdgcn_mfma_f32_16x16x32_bf16(af[k2][0], bfr[j], acc[0][j], 0, 0, 0);
                    acc[1][j] = __builtin_amdgcn_mfma_f32_16x16x32_bf16(af[k2][1], bfr[j], acc[1][j], 0, 0, 0);
                }
            }
        }
    }

    // C-write: C/D layout col=lane&15, row=quad*4+r
    float* dst = partial + (size_t)ks * NSAMP * 256;
#pragma unroll
    for (int i = 0; i < 2; ++i)
#pragma unroll
        for (int j = 0; j < 4; ++j)
#pragma unroll
            for (int r = 0; r < 4; ++r) {
                const int row = wm0 + i * 16 + quad * 4 + r;
                const int col = wn0 + j * 16 + lr;
                dst[(size_t)(b0 + row) * 256 + m0 + col] = acc[i][j][r];
            }
}

// ==================== small-layer GEMM (M=16) — previous structure ====================
template<int BM, int BN, int WROWS, int WCOLS>
__global__ __launch_bounds__(256, 2) void gemm_k(
    const ushort* __restrict__ wWb, const float* __restrict__ h,
    const float* __restrict__ xT, float* __restrict__ partial,
    int S, int M, int iw, int ksplit, int btiles, int ntiles)
{
    constexpr int SM = BM / WROWS / 16;
    constexpr int SN = BN / WCOLS / 16;
    constexpr int ASLOTS = BM * 8 / 256;
    constexpr int LDA = 72;

    __shared__ ushort As[BM][LDA];
    __shared__ ushort Bs[BN][LDA];

    const int tid = threadIdx.x;
    const int bt = blockIdx.x % btiles;
    const int nt = (blockIdx.x / btiles) % ntiles;
    const int ks = blockIdx.x / (btiles * ntiles);
    const int b0 = bt * BM;
    const int m0 = nt * BN;
    const int total_s = S + 3;
    const int base = total_s / ksplit;
    const int rem = total_s - base * ksplit;
    const int s0 = ks * base + min(ks, rem);
    const int s1 = s0 + base + (ks < rem ? 1 : 0);

    const int lane = tid & 63;
    const int wave = tid >> 6;
    const int quad = lane >> 4;
    const int lr = lane & 15;
    const int wm0 = (wave / WCOLS) * (BM / WROWS);
    const int wn0 = (wave % WCOLS) * (BN / WCOLS);

    const int tb = tid >> 3;
    const int teg = tid & 7;

    float hreg[ASLOTS][2][8];
#pragma unroll
    for (int k2 = 0; k2 < ASLOTS; ++k2) {
        int b = tb + 32 * k2;
#pragma unroll
        for (int p = 0; p < 2; ++p) {
            const float* src = h + (size_t)(b0 + b) * 1280 + (size_t)iw * E_ + p * 64 + teg * 8;
            float4 v0 = *(const float4*)(src);
            float4 v1 = *(const float4*)(src + 4);
            hreg[k2][p][0] = v0.x; hreg[k2][p][1] = v0.y; hreg[k2][p][2] = v0.z; hreg[k2][p][3] = v0.w;
            hreg[k2][p][4] = v1.x; hreg[k2][p][5] = v1.y; hreg[k2][p][6] = v1.z; hreg[k2][p][7] = v1.w;
        }
    }

    floatx4 acc[SM][SN];
#pragma unroll
    for (int i = 0; i < SM; ++i)
#pragma unroll
        for (int j = 0; j < SN; ++j)
            acc[i][j] = (floatx4){0.f, 0.f, 0.f, 0.f};

    for (int s = s0; s < s1; ++s) {
        float xv[ASLOTS];
        if (s < S) {
#pragma unroll
            for (int k2 = 0; k2 < ASLOTS; ++k2)
                xv[k2] = xT[(size_t)s * NSAMP + b0 + tb + 32 * k2];
        }

#pragma unroll
        for (int p = 0; p < 2; ++p) {
            if (s < S) {
#pragma unroll
                for (int k2 = 0; k2 < ASLOTS; ++k2) {
                    union { ushort o[8]; uint4 v; } u;
#pragma unroll
                    for (int j = 0; j < 8; ++j) u.o[j] = f2b(xv[k2] * hreg[k2][p][j]);
                    *(uint4*)&As[tb + 32 * k2][teg * 8] = u.v;
                }
            } else if (s == S) {
#pragma unroll
                for (int k2 = 0; k2 < ASLOTS; ++k2) {
                    const float* src = h + (size_t)(b0 + tb + 32 * k2) * 1280
                                         + (size_t)(iw + 1) * E_ + p * 64 + teg * 8;
                    float4 v0 = *(const float4*)(src);
                    float4 v1 = *(const float4*)(src + 4);
                    union { ushort o[8]; uint4 v; } u;
                    u.o[0] = f2b(v0.x); u.o[1] = f2b(v0.y); u.o[2] = f2b(v0.z); u.o[3] = f2b(v0.w);
                    u.o[4] = f2b(v1.x); u.o[5] = f2b(v1.y); u.o[6] = f2b(v1.z); u.o[7] = f2b(v1.w);
                    *(uint4*)&As[tb + 32 * k2][teg * 8] = u.v;
                }
            } else {
                int j0 = (s - S - 1) * 128 + p * 64 + teg * 8;
#pragma unroll
                for (int k2 = 0; k2 < ASLOTS; ++k2) {
                    int b = b0 + tb + 32 * k2;
                    union { ushort o[8]; uint4 v; } u;
#pragma unroll
                    for (int jj = 0; jj < 8; ++jj) {
                        int sp = j0 + jj;
                        u.o[jj] = (sp < S) ? f2b(xT[(size_t)sp * NSAMP + b]) : (ushort)0;
                    }
                    *(uint4*)&As[tb + 32 * k2][teg * 8] = u.v;
                }
            }
#pragma unroll
            for (int slot = tid; slot < BN * 8; slot += 256) {
                int m = slot >> 3, eg2 = slot & 7;
                *(uint4*)&Bs[m][eg2 * 8] =
                    *(const uint4*)(wWb + ((size_t)s * M + m0 + m) * E_ + p * 64 + eg2 * 8);
            }
            __syncthreads();
#pragma unroll
            for (int kk = 0; kk < 2; ++kk) {
                short8 af[SM], bfr[SN];
#pragma unroll
                for (int i = 0; i < SM; ++i)
                    af[i] = *(const short8*)&As[wm0 + i * 16 + lr][kk * 32 + quad * 8];
#pragma unroll
                for (int j = 0; j < SN; ++j)
                    bfr[j] = *(const short8*)&Bs[wn0 + j * 16 + lr][kk * 32 + quad * 8];
#pragma unroll
                for (int i = 0; i < SM; ++i)
#pragma unroll
                    for (int j = 0; j < SN; ++j)
                        acc[i][j] = __builtin_amdgcn_mfma_f32_16x16x32_bf16(af[i], bfr[j], acc[i][j], 0, 0, 0);
            }
            __syncthreads();
        }
    }

    float* dst = partial + (size_t)ks * NSAMP * M;
#pragma unroll
    for (int i = 0; i < SM; ++i)
#pragma unroll
        for (int j = 0; j < SN; ++j)
#pragma unroll
            for (int r = 0; r < 4; ++r) {
                int row = wm0 + i * 16 + quad * 4 + r;
                int col = wn0 + j * 16 + lr;
                dst[(size_t)(b0 + row) * M + m0 + col] = acc[i][j][r];
            }
}

// -------------------- reduce partials + bb (+ReLU), emit xT fp32 for next layer --------------
__global__ void reduce_mid(const float* __restrict__ partial, const float* __restrict__ bb,
                           float* __restrict__ xTn, int KS, int relu)
{
    __shared__ float t[32][33];
    const int b0 = (blockIdx.x >> 3) * 32;
    const int m0 = (blockIdx.x & 7) * 32;
    const int mo = threadIdx.x & 31;
    const int bs0 = threadIdx.x >> 5;   // 0..7
    const float bv = bb[m0 + mo];
#pragma unroll
    for (int r = 0; r < 4; ++r) {
        const int bs = bs0 + 8 * r;
        const size_t off = (size_t)(b0 + bs) * 256 + m0 + mo;
        float a0 = 0.f, a1 = 0.f, a2 = 0.f, a3 = 0.f;
#pragma unroll
        for (int k = 0; k < 16; k += 4) {
            a0 += partial[(size_t)(k + 0) * (NSAMP * 256) + off];
            a1 += partial[(size_t)(k + 1) * (NSAMP * 256) + off];
            a2 += partial[(size_t)(k + 2) * (NSAMP * 256) + off];
            a3 += partial[(size_t)(k + 3) * (NSAMP * 256) + off];
        }
        float a = (a0 + a1) + (a2 + a3) + bv;
        if (relu) a = fmaxf(a, 0.f);
        t[bs][mo] = a;
    }
    __syncthreads();
    const int bo = threadIdx.x & 31;
    const int ms0 = threadIdx.x >> 5;
#pragma unroll
    for (int r = 0; r < 4; ++r) {
        const int ms = ms0 + 8 * r;
        xTn[(size_t)(m0 + ms) * NSAMP + b0 + bo] = t[bo][ms];
    }
}

// -------------------- final layer reduce -> d_out (fp32, ReLU) --------------------
__global__ void reduce_out(const float* __restrict__ partial, const float* __restrict__ bb,
                           float* __restrict__ out, int KS)
{
    int idx = blockIdx.x * 256 + threadIdx.x;   // < 2048*16
    float a0 = 0.f, a1 = 0.f, a2 = 0.f, a3 = 0.f;
#pragma unroll
    for (int k = 0; k < 64; k += 4) {
        a0 += partial[(size_t)(k + 0) * (NSAMP * 16) + idx];
        a1 += partial[(size_t)(k + 1) * (NSAMP * 16) + idx];
        a2 += partial[(size_t)(k + 2) * (NSAMP * 16) + idx];
        a3 += partial[(size_t)(k + 3) * (NSAMP * 16) + idx];
    }
    out[idx] = fmaxf((a0 + a1) + (a2 + a3) + bb[idx & 15], 0.f);
}

extern "C" void kernel_launch(void* const* d_in, const int* in_sizes, int n_in,
                              void* d_out, int out_size, void* d_ws, size_t ws_size,
                              hipStream_t stream)
{
    const float* input = (const float*)d_in[0];
    const float* l1W   = (const float*)d_in[1];
    const float* l1b   = (const float*)d_in[2];

    char* ws = (char*)d_ws;
    // layout (bytes): wWb 16.98M | h 10.49M | xT0 2M | xT1 2M | partial 33.55M = 65.2MB
    ushort* wWb = (ushort*)(ws + 0);
    float* h    = (float*)(ws + 16975872);
    float* xT0  = (float*)(ws + 27461632);
    float* xT1  = (float*)(ws + 29558784);
    float* part = (float*)(ws + 31655936);

    hipLaunchKernelGGL(hyper_h, dim3(2048 * 5), dim3(256), 0, stream, input, l1W, l1b, h);
    hipLaunchKernelGGL(x0_t, dim3(176 * 2048 / 256), dim3(256), 0, stream, input, xT0);

    const int S_[5] = {176, 256, 256, 256, 256};
    const int M_[5] = {256, 256, 256, 256, 16};
    float* xt[2] = {xT0, xT1};

    for (int i = 0; i < 5; ++i) {
        const float* wW = (const float*)d_in[3 + 4 * i];
        const float* wb = (const float*)d_in[4 + 4 * i];
        const float* bW = (const float*)d_in[5 + 4 * i];
        const float* bb = (const float*)d_in[6 + 4 * i];
        float* xin = xt[i & 1];
        int ntot = (S_[i] + 3) * M_[i] * E_;
        hipLaunchKernelGGL(cvt_layer, dim3(ntot / 2048), dim3(256), 0, stream,
                           wW, wb, bW, wWb, S_[i], M_[i]);

        if (M_[i] == 256) {
            const int btiles = 32, ntiles = 2, ksplit = 16;
            hipLaunchKernelGGL(gemm_big, dim3(btiles * ntiles * ksplit), dim3(256), 0, stream,
                               wWb, h, xin, part, S_[i], 2 * i, ksplit, btiles, ntiles);
            hipLaunchKernelGGL(reduce_mid, dim3(512), dim3(256), 0, stream,
                               part, bb, xt[(i + 1) & 1], ksplit, (i < 3) ? 1 : 0);
        } else {
            const int btiles = 8, ntiles = 1, ksplit = 64;
            hipLaunchKernelGGL((gemm_k<256, 16, 4, 1>), dim3(btiles * ntiles * ksplit), dim3(256), 0, stream,
                               wWb, h, xin, part, S_[i], 16, 2 * i, ksplit, btiles, ntiles);
            hipLaunchKernelGGL(reduce_out, dim3(128), dim3(256), 0, stream,
                               part, bb, (float*)d_out, ksplit);
        }
    }
}

// Round 8
// 607.737 us; speedup vs baseline: 1.6210x; 1.6210x over previous
//
#include <hip/hip_runtime.h>
#include <hip/hip_bf16.h>

#define E_ 128
#define NSAMP 2048

typedef __attribute__((ext_vector_type(8))) short short8;
typedef __attribute__((ext_vector_type(4))) float floatx4;

__device__ __forceinline__ ushort f2b(float f) {
    union { __hip_bfloat16 h; ushort u; } cv;
    cv.h = __float2bfloat16(f);
    return cv.u;
}

__device__ __forceinline__ void gload_lds16(const ushort* g, ushort* l) {
    __builtin_amdgcn_global_load_lds(
        (const __attribute__((address_space(1))) void*)g,
        (__attribute__((address_space(3))) void*)l, 16, 0, 0);
}

// -------------------- h = ReLU(ids @ l1W^T + l1b), fp32 --------------------
__global__ void hyper_h(const float* __restrict__ input, const float* __restrict__ l1W,
                        const float* __restrict__ l1b, float* __restrict__ h)
{
    int b = blockIdx.x / 5;
    int o = (blockIdx.x % 5) * 256 + threadIdx.x;
    const float* ids = input + (size_t)b * 192 + 176;
    const float* w = l1W + (size_t)o * 16;
    float a = l1b[o];
#pragma unroll
    for (int i = 0; i < 16; i += 4) {
        float4 wv = *(const float4*)(w + i);
        a += ids[i] * wv.x + ids[i + 1] * wv.y + ids[i + 2] * wv.z + ids[i + 3] * wv.w;
    }
    h[(size_t)b * 1280 + o] = fmaxf(a, 0.f);
}

// -------------------- xT0[s][b] = input[b][s]  (s < 176), fp32 --------------------
__global__ void x0_t(const float* __restrict__ input, float* __restrict__ xT0)
{
    int idx = blockIdx.x * 256 + threadIdx.x;   // < 176*2048
    int s = idx >> 11, b = idx & 2047;
    xT0[idx] = input[(size_t)b * 192 + s];
}

// ---------- fused per-layer weight prep: wW -> bf16, plus 3 virtual B-slices ----------
__global__ void cvt_layer(const float* __restrict__ wW, const float* __restrict__ wb,
                          const float* __restrict__ bW, ushort* __restrict__ dst,
                          int S, int M)
{
    int i = (blockIdx.x * 256 + threadIdx.x) * 8;       // 8 dst elements per thread
    const int nW = S * M * E_;
    union { ushort o[8]; uint4 v; } u;
    if (i < nW) {
        float4 a = *(const float4*)(wW + i);
        float4 b = *(const float4*)(wW + i + 4);
        u.o[0] = f2b(a.x); u.o[1] = f2b(a.y); u.o[2] = f2b(a.z); u.o[3] = f2b(a.w);
        u.o[4] = f2b(b.x); u.o[5] = f2b(b.y); u.o[6] = f2b(b.z); u.o[7] = f2b(b.w);
    } else {
        int rem = i - nW;                   // < 3*M*E_
        int slice = rem / (M * E_);
        int r2 = rem - slice * (M * E_);
        int m = r2 >> 7, e = r2 & 127;      // E_ = 128
        if (slice == 0) {
            const float* src = bW + (size_t)m * E_ + e;
            float4 a = *(const float4*)(src);
            float4 b = *(const float4*)(src + 4);
            u.o[0] = f2b(a.x); u.o[1] = f2b(a.y); u.o[2] = f2b(a.z); u.o[3] = f2b(a.w);
            u.o[4] = f2b(b.x); u.o[5] = f2b(b.y); u.o[6] = f2b(b.z); u.o[7] = f2b(b.w);
        } else {
#pragma unroll
            for (int jj = 0; jj < 8; ++jj) {
                int s = (slice - 1) * 128 + e + jj;
                u.o[jj] = (s < S) ? f2b(wb[(size_t)s * M + m]) : (ushort)0;
            }
        }
    }
    *(uint4*)(dst + i) = u.v;
}

// ==================== big-layer GEMM (M=256): BM=128 x BN=64, 1024 blocks, 4/CU ====================
// 256 threads (4 waves), wave owns 32 rows x all 64 cols. A = x*h in registers
// (hreg 64 fp32/lane, ALL indices compile-time -- r7's runtime-P indexing spilled, rule #20).
// B: ring-2 x 8KB (BK=64, 64 B-rows), 2-deep prefetch, steady s_waitcnt vmcnt(2),
// refill Bs[P] after reads-done barrier (WAR-safe; buffer index t&1 == P, static).
// LDS 25.1KB, ~80 VGPR -> grid 1024 = 4 blocks/CU = 16 waves/CU = 4 waves/SIMD
// (2x the 65us rounds). This is the first clean occupancy test: r5 spilled (bounds cap),
// r6 was 8-wave lockstep, r7 spilled (dynamic index).
__global__ __launch_bounds__(256, 2) void gemm_big(
    const ushort* __restrict__ wWb, const float* __restrict__ h,
    const float* __restrict__ xT, float* __restrict__ partial,
    int S, int iw, int ksplit, int btiles, int ntiles)
{
    __shared__ __align__(16) ushort Bs[2][64 * 64];   // ring-2, 8KB each
    __shared__ __align__(16) float xs[17 * 128];

    const int tid = threadIdx.x;
    // XCD-aware decode: combo (nt,ks) pinned to one XCD, its 16 bt-blocks contiguous there.
    const int bid = blockIdx.x;
    const int xcd = bid & 7;
    const int jj_ = bid >> 3;
    const int combo = xcd + 8 * (jj_ / btiles);
    const int bt = jj_ % btiles;
    const int nt = combo % ntiles;
    const int ks = combo / ntiles;
    const int b0 = bt * 128;
    const int m0 = nt * 64;
    const int total_s = S + 3;
    const int base = total_s / ksplit;
    const int rem = total_s - base * ksplit;
    const int s0 = ks * base + min(ks, rem);
    const int s1v = s0 + base + (ks < rem ? 1 : 0);
    const int sE = min(s1v, S);     // main loop covers [s0, sE)
    const int ns = sE - s0;
    const int T = 2 * ns;           // BK=64 phases

    const int lane = tid & 63;
    const int wave = tid >> 6;      // 0..3
    const int quad = lane >> 4;
    const int lr = lane & 15;
    const int wm0 = wave * 32;      // wave rows: 32 of 128; cols: all 64

    const int brow = lane >> 3;         // B-DMA local row (0..7)
    const int bgg = (lane & 7) ^ brow;  // global e-group for this lane's slot

    // h fragments: hreg[i][P][k2][j] = h[b0+wm0+i*16+lr][iw*128 + P*64 + k2*32 + quad*8 + j]
    float hreg[2][2][2][8];
#pragma unroll
    for (int i = 0; i < 2; ++i)
#pragma unroll
        for (int p = 0; p < 2; ++p)
#pragma unroll
            for (int k2 = 0; k2 < 2; ++k2) {
                const float* src = h + (size_t)(b0 + wm0 + i * 16 + lr) * 1280
                                     + (size_t)iw * E_ + p * 64 + k2 * 32 + quad * 8;
                float4 v0 = *(const float4*)(src);
                float4 v1 = *(const float4*)(src + 4);
                hreg[i][p][k2][0] = v0.x; hreg[i][p][k2][1] = v0.y;
                hreg[i][p][k2][2] = v0.z; hreg[i][p][k2][3] = v0.w;
                hreg[i][p][k2][4] = v1.x; hreg[i][p][k2][5] = v1.y;
                hreg[i][p][k2][6] = v1.z; hreg[i][p][k2][7] = v1.w;
            }

    // stage x-slice: xs[si][b_local], 128 rows per block
    for (int idx = tid; idx < ns * 128; idx += 256) {
        int j = idx >> 7, bb2 = idx & 127;
        xs[idx] = xT[(size_t)(s0 + j) * NSAMP + b0 + bb2];
    }

    floatx4 acc[2][4];
#pragma unroll
    for (int i = 0; i < 2; ++i)
#pragma unroll
        for (int j = 0; j < 4; ++j)
            acc[i][j] = (floatx4){0.f, 0.f, 0.f, 0.f};

    // BK=64 phase DMA: 2 gload_lds per wave (4 waves x 16 rows = 64 B-rows)
    auto dmaP = [&](int s, int p, ushort* buf) {
#pragma unroll
        for (int rnd = 0; rnd < 2; ++rnd) {
            int rloc = wave * 16 + rnd * 8;
            const ushort* gp = wWb + ((size_t)s * 256 + m0 + rloc + brow) * E_ + p * 64 + bgg * 8;
            gload_lds16(gp, buf + (size_t)rloc * 64 + lane * 8);
        }
    };

    // prologue: drain hreg/xs loads, then 2 phases of DMA in flight (4 loads/wave)
    __builtin_amdgcn_sched_barrier(0);
    __syncthreads();
    __builtin_amdgcn_sched_barrier(0);
    if (T > 0) dmaP(s0, 0, Bs[0]);
    if (T > 1) dmaP(s0, 1, Bs[1]);

    for (int si = 0; si < ns; ++si) {
        const float xr0 = xs[si * 128 + wm0 + lr];
        const float xr1 = xs[si * 128 + wm0 + 16 + lr];
        const bool more = (si + 1 < ns);
#pragma unroll
        for (int P = 0; P < 2; ++P) {
            // wait: phase t=2si+P staged; next phase's 2 loads may stay in flight
            if (P == 0 || more) { asm volatile("s_waitcnt vmcnt(2)" ::: "memory"); }
            else                { asm volatile("s_waitcnt vmcnt(0)" ::: "memory"); }
            __builtin_amdgcn_sched_barrier(0);
            __builtin_amdgcn_s_barrier();          // barrier1: phase staged for all waves
            __builtin_amdgcn_sched_barrier(0);

            const ushort* bcur = Bs[P];            // buffer index t&1 == P (static)
            __builtin_amdgcn_s_setprio(1);
#pragma unroll
            for (int k2 = 0; k2 < 2; ++k2) {
                const int swz = ((k2 * 4 + quad) ^ (lr & 7)) * 8;
                short8 bfr[4];
#pragma unroll
                for (int j = 0; j < 4; ++j)
                    bfr[j] = *(const short8*)&bcur[(size_t)(j * 16 + lr) * 64 + swz];
                short8 a0, a1;
#pragma unroll
                for (int jj = 0; jj < 8; ++jj) {
                    a0[jj] = (short)f2b(xr0 * hreg[0][P][k2][jj]);
                    a1[jj] = (short)f2b(xr1 * hreg[1][P][k2][jj]);
                }
#pragma unroll
                for (int j = 0; j < 4; ++j) {
                    acc[0][j] = __builtin_amdgcn_mfma_f32_16x16x32_bf16(a0, bfr[j], acc[0][j], 0, 0, 0);
                    acc[1][j] = __builtin_amdgcn_mfma_f32_16x16x32_bf16(a1, bfr[j], acc[1][j], 0, 0, 0);
                }
            }
            __builtin_amdgcn_s_setprio(0);
            __builtin_amdgcn_sched_barrier(0);
            __builtin_amdgcn_s_barrier();          // barrier2: all waves done reading Bs[P]
            __builtin_amdgcn_sched_barrier(0);

            if (more) dmaP(s0 + si + 1, P, Bs[P]); // refill for phase t+2 (same parity, WAR-safe)
        }
    }

    // ---- virtual slices s in [S, s1v): non-pipelined (only last-ks blocks) ----
    for (int s = sE; s < s1v; ++s) {
        for (int p = 0; p < 2; ++p) {
            __syncthreads();            // full drain; previous reads complete
            dmaP(s, p, Bs[0]);
            short8 af[2][2];            // [k2][i]
            if (s == S) {
#pragma unroll
                for (int k2 = 0; k2 < 2; ++k2)
#pragma unroll
                    for (int i = 0; i < 2; ++i) {
                        const float* src = h + (size_t)(b0 + wm0 + i * 16 + lr) * 1280
                                             + (size_t)(iw + 1) * E_ + p * 64 + k2 * 32 + quad * 8;
                        float4 v0 = *(const float4*)(src);
                        float4 v1 = *(const float4*)(src + 4);
                        af[k2][i][0] = (short)f2b(v0.x); af[k2][i][1] = (short)f2b(v0.y);
                        af[k2][i][2] = (short)f2b(v0.z); af[k2][i][3] = (short)f2b(v0.w);
                        af[k2][i][4] = (short)f2b(v1.x); af[k2][i][5] = (short)f2b(v1.y);
                        af[k2][i][6] = (short)f2b(v1.z); af[k2][i][7] = (short)f2b(v1.w);
                    }
            } else {
                const int jbase = (s - S - 1) * 128 + p * 64;
#pragma unroll
                for (int k2 = 0; k2 < 2; ++k2)
#pragma unroll
                    for (int i = 0; i < 2; ++i) {
                        const int b = b0 + wm0 + i * 16 + lr;
#pragma unroll
                        for (int jj = 0; jj < 8; ++jj) {
                            const int sp = jbase + k2 * 32 + quad * 8 + jj;
                            af[k2][i][jj] = (sp < S) ? (short)f2b(xT[(size_t)sp * NSAMP + b]) : (short)0;
                        }
                    }
            }
            __syncthreads();            // DMA + af loads drained
#pragma unroll
            for (int k2 = 0; k2 < 2; ++k2) {
                const int swz = ((k2 * 4 + quad) ^ (lr & 7)) * 8;
                short8 bfr[4];
#pragma unroll
                for (int j = 0; j < 4; ++j)
                    bfr[j] = *(const short8*)&Bs[0][(size_t)(j * 16 + lr) * 64 + swz];
#pragma unroll
                for (int j = 0; j < 4; ++j) {
                    acc[0][j] = __builtin_amdgcn_mfma_f32_16x16x32_bf16(af[k2][0], bfr[j], acc[0][j], 0, 0, 0);
                    acc[1][j] = __builtin_amdgcn_mfma_f32_16x16x32_bf16(af[k2][1], bfr[j], acc[1][j], 0, 0, 0);
                }
            }
        }
    }

    // C-write: C/D layout col=lane&15, row=quad*4+r
    float* dst = partial + (size_t)ks * NSAMP * 256;
#pragma unroll
    for (int i = 0; i < 2; ++i)
#pragma unroll
        for (int j = 0; j < 4; ++j)
#pragma unroll
            for (int r = 0; r < 4; ++r) {
                const int row = wm0 + i * 16 + quad * 4 + r;
                const int col = j * 16 + lr;
                dst[(size_t)(b0 + row) * 256 + m0 + col] = acc[i][j][r];
            }
}

// ==================== small-layer GEMM (M=16) — previous structure ====================
template<int BM, int BN, int WROWS, int WCOLS>
__global__ __launch_bounds__(256, 2) void gemm_k(
    const ushort* __restrict__ wWb, const float* __restrict__ h,
    const float* __restrict__ xT, float* __restrict__ partial,
    int S, int M, int iw, int ksplit, int btiles, int ntiles)
{
    constexpr int SM = BM / WROWS / 16;
    constexpr int SN = BN / WCOLS / 16;
    constexpr int ASLOTS = BM * 8 / 256;
    constexpr int LDA = 72;

    __shared__ ushort As[BM][LDA];
    __shared__ ushort Bs[BN][LDA];

    const int tid = threadIdx.x;
    const int bt = blockIdx.x % btiles;
    const int nt = (blockIdx.x / btiles) % ntiles;
    const int ks = blockIdx.x / (btiles * ntiles);
    const int b0 = bt * BM;
    const int m0 = nt * BN;
    const int total_s = S + 3;
    const int base = total_s / ksplit;
    const int rem = total_s - base * ksplit;
    const int s0 = ks * base + min(ks, rem);
    const int s1 = s0 + base + (ks < rem ? 1 : 0);

    const int lane = tid & 63;
    const int wave = tid >> 6;
    const int quad = lane >> 4;
    const int lr = lane & 15;
    const int wm0 = (wave / WCOLS) * (BM / WROWS);
    const int wn0 = (wave % WCOLS) * (BN / WCOLS);

    const int tb = tid >> 3;
    const int teg = tid & 7;

    float hreg[ASLOTS][2][8];
#pragma unroll
    for (int k2 = 0; k2 < ASLOTS; ++k2) {
        int b = tb + 32 * k2;
#pragma unroll
        for (int p = 0; p < 2; ++p) {
            const float* src = h + (size_t)(b0 + b) * 1280 + (size_t)iw * E_ + p * 64 + teg * 8;
            float4 v0 = *(const float4*)(src);
            float4 v1 = *(const float4*)(src + 4);
            hreg[k2][p][0] = v0.x; hreg[k2][p][1] = v0.y; hreg[k2][p][2] = v0.z; hreg[k2][p][3] = v0.w;
            hreg[k2][p][4] = v1.x; hreg[k2][p][5] = v1.y; hreg[k2][p][6] = v1.z; hreg[k2][p][7] = v1.w;
        }
    }

    floatx4 acc[SM][SN];
#pragma unroll
    for (int i = 0; i < SM; ++i)
#pragma unroll
        for (int j = 0; j < SN; ++j)
            acc[i][j] = (floatx4){0.f, 0.f, 0.f, 0.f};

    for (int s = s0; s < s1; ++s) {
        float xv[ASLOTS];
        if (s < S) {
#pragma unroll
            for (int k2 = 0; k2 < ASLOTS; ++k2)
                xv[k2] = xT[(size_t)s * NSAMP + b0 + tb + 32 * k2];
        }

#pragma unroll
        for (int p = 0; p < 2; ++p) {
            if (s < S) {
#pragma unroll
                for (int k2 = 0; k2 < ASLOTS; ++k2) {
                    union { ushort o[8]; uint4 v; } u;
#pragma unroll
                    for (int j = 0; j < 8; ++j) u.o[j] = f2b(xv[k2] * hreg[k2][p][j]);
                    *(uint4*)&As[tb + 32 * k2][teg * 8] = u.v;
                }
            } else if (s == S) {
#pragma unroll
                for (int k2 = 0; k2 < ASLOTS; ++k2) {
                    const float* src = h + (size_t)(b0 + tb + 32 * k2) * 1280
                                         + (size_t)(iw + 1) * E_ + p * 64 + teg * 8;
                    float4 v0 = *(const float4*)(src);
                    float4 v1 = *(const float4*)(src + 4);
                    union { ushort o[8]; uint4 v; } u;
                    u.o[0] = f2b(v0.x); u.o[1] = f2b(v0.y); u.o[2] = f2b(v0.z); u.o[3] = f2b(v0.w);
                    u.o[4] = f2b(v1.x); u.o[5] = f2b(v1.y); u.o[6] = f2b(v1.z); u.o[7] = f2b(v1.w);
                    *(uint4*)&As[tb + 32 * k2][teg * 8] = u.v;
                }
            } else {
                int j0 = (s - S - 1) * 128 + p * 64 + teg * 8;
#pragma unroll
                for (int k2 = 0; k2 < ASLOTS; ++k2) {
                    int b = b0 + tb + 32 * k2;
                    union { ushort o[8]; uint4 v; } u;
#pragma unroll
                    for (int jj = 0; jj < 8; ++jj) {
                        int sp = j0 + jj;
                        u.o[jj] = (sp < S) ? f2b(xT[(size_t)sp * NSAMP + b]) : (ushort)0;
                    }
                    *(uint4*)&As[tb + 32 * k2][teg * 8] = u.v;
                }
            }
#pragma unroll
            for (int slot = tid; slot < BN * 8; slot += 256) {
                int m = slot >> 3, eg2 = slot & 7;
                *(uint4*)&Bs[m][eg2 * 8] =
                    *(const uint4*)(wWb + ((size_t)s * M + m0 + m) * E_ + p * 64 + eg2 * 8);
            }
            __syncthreads();
#pragma unroll
            for (int kk = 0; kk < 2; ++kk) {
                short8 af[SM], bfr[SN];
#pragma unroll
                for (int i = 0; i < SM; ++i)
                    af[i] = *(const short8*)&As[wm0 + i * 16 + lr][kk * 32 + quad * 8];
#pragma unroll
                for (int j = 0; j < SN; ++j)
                    bfr[j] = *(const short8*)&Bs[wn0 + j * 16 + lr][kk * 32 + quad * 8];
#pragma unroll
                for (int i = 0; i < SM; ++i)
#pragma unroll
                    for (int j = 0; j < SN; ++j)
                        acc[i][j] = __builtin_amdgcn_mfma_f32_16x16x32_bf16(af[i], bfr[j], acc[i][j], 0, 0, 0);
            }
            __syncthreads();
        }
    }

    float* dst = partial + (size_t)ks * NSAMP * M;
#pragma unroll
    for (int i = 0; i < SM; ++i)
#pragma unroll
        for (int j = 0; j < SN; ++j)
#pragma unroll
            for (int r = 0; r < 4; ++r) {
                int row = wm0 + i * 16 + quad * 4 + r;
                int col = wn0 + j * 16 + lr;
                dst[(size_t)(b0 + row) * M + m0 + col] = acc[i][j][r];
            }
}

// -------------------- reduce partials + bb (+ReLU), emit xT fp32 for next layer --------------
__global__ void reduce_mid(const float* __restrict__ partial, const float* __restrict__ bb,
                           float* __restrict__ xTn, int KS, int relu)
{
    __shared__ float t[32][33];
    const int b0 = (blockIdx.x >> 3) * 32;
    const int m0 = (blockIdx.x & 7) * 32;
    const int mo = threadIdx.x & 31;
    const int bs0 = threadIdx.x >> 5;   // 0..7
    const float bv = bb[m0 + mo];
#pragma unroll
    for (int r = 0; r < 4; ++r) {
        const int bs = bs0 + 8 * r;
        const size_t off = (size_t)(b0 + bs) * 256 + m0 + mo;
        float a0 = 0.f, a1 = 0.f, a2 = 0.f, a3 = 0.f;
#pragma unroll
        for (int k = 0; k < 16; k += 4) {
            a0 += partial[(size_t)(k + 0) * (NSAMP * 256) + off];
            a1 += partial[(size_t)(k + 1) * (NSAMP * 256) + off];
            a2 += partial[(size_t)(k + 2) * (NSAMP * 256) + off];
            a3 += partial[(size_t)(k + 3) * (NSAMP * 256) + off];
        }
        float a = (a0 + a1) + (a2 + a3) + bv;
        if (relu) a = fmaxf(a, 0.f);
        t[bs][mo] = a;
    }
    __syncthreads();
    const int bo = threadIdx.x & 31;
    const int ms0 = threadIdx.x >> 5;
#pragma unroll
    for (int r = 0; r < 4; ++r) {
        const int ms = ms0 + 8 * r;
        xTn[(size_t)(m0 + ms) * NSAMP + b0 + bo] = t[bo][ms];
    }
}

// -------------------- final layer reduce -> d_out (fp32, ReLU) --------------------
__global__ void reduce_out(const float* __restrict__ partial, const float* __restrict__ bb,
                           float* __restrict__ out, int KS)
{
    int idx = blockIdx.x * 256 + threadIdx.x;   // < 2048*16
    float a0 = 0.f, a1 = 0.f, a2 = 0.f, a3 = 0.f;
#pragma unroll
    for (int k = 0; k < 64; k += 4) {
        a0 += partial[(size_t)(k + 0) * (NSAMP * 16) + idx];
        a1 += partial[(size_t)(k + 1) * (NSAMP * 16) + idx];
        a2 += partial[(size_t)(k + 2) * (NSAMP * 16) + idx];
        a3 += partial[(size_t)(k + 3) * (NSAMP * 16) + idx];
    }
    out[idx] = fmaxf((a0 + a1) + (a2 + a3) + bb[idx & 15], 0.f);
}

extern "C" void kernel_launch(void* const* d_in, const int* in_sizes, int n_in,
                              void* d_out, int out_size, void* d_ws, size_t ws_size,
                              hipStream_t stream)
{
    const float* input = (const float*)d_in[0];
    const float* l1W   = (const float*)d_in[1];
    const float* l1b   = (const float*)d_in[2];

    char* ws = (char*)d_ws;
    // layout (bytes): wWb 16.98M | h 10.49M | xT0 2M | xT1 2M | partial 33.55M = 65.2MB
    ushort* wWb = (ushort*)(ws + 0);
    float* h    = (float*)(ws + 16975872);
    float* xT0  = (float*)(ws + 27461632);
    float* xT1  = (float*)(ws + 29558784);
    float* part = (float*)(ws + 31655936);

    hipLaunchKernelGGL(hyper_h, dim3(2048 * 5), dim3(256), 0, stream, input, l1W, l1b, h);
    hipLaunchKernelGGL(x0_t, dim3(176 * 2048 / 256), dim3(256), 0, stream, input, xT0);

    const int S_[5] = {176, 256, 256, 256, 256};
    const int M_[5] = {256, 256, 256, 256, 16};
    float* xt[2] = {xT0, xT1};

    for (int i = 0; i < 5; ++i) {
        const float* wW = (const float*)d_in[3 + 4 * i];
        const float* wb = (const float*)d_in[4 + 4 * i];
        const float* bW = (const float*)d_in[5 + 4 * i];
        const float* bb = (const float*)d_in[6 + 4 * i];
        float* xin = xt[i & 1];
        int ntot = (S_[i] + 3) * M_[i] * E_;
        hipLaunchKernelGGL(cvt_layer, dim3(ntot / 2048), dim3(256), 0, stream,
                           wW, wb, bW, wWb, S_[i], M_[i]);

        if (M_[i] == 256) {
            const int btiles = 16, ntiles = 4, ksplit = 16;
            hipLaunchKernelGGL(gemm_big, dim3(btiles * ntiles * ksplit), dim3(256), 0, stream,
                               wWb, h, xin, part, S_[i], 2 * i, ksplit, btiles, ntiles);
            hipLaunchKernelGGL(reduce_mid, dim3(512), dim3(256), 0, stream,
                               part, bb, xt[(i + 1) & 1], ksplit, (i < 3) ? 1 : 0);
        } else {
            const int btiles = 8, ntiles = 1, ksplit = 64;
            hipLaunchKernelGGL((gemm_k<256, 16, 4, 1>), dim3(btiles * ntiles * ksplit), dim3(256), 0, stream,
                               wWb, h, xin, part, S_[i], 16, 2 * i, ksplit, btiles, ntiles);
            hipLaunchKernelGGL(reduce_out, dim3(128), dim3(256), 0, stream,
                               part, bb, (float*)d_out, ksplit);
        }
    }
}

// Round 9
// 509.657 us; speedup vs baseline: 1.9329x; 1.1924x over previous
//
#include <hip/hip_runtime.h>
#include <hip/hip_bf16.h>

#define E_ 128
#define NSAMP 2048

typedef __attribute__((ext_vector_type(8))) short short8;
typedef __attribute__((ext_vector_type(4))) float floatx4;

__device__ __forceinline__ ushort f2b(float f) {
    union { __hip_bfloat16 h; ushort u; } cv;
    cv.h = __float2bfloat16(f);
    return cv.u;
}

__device__ __forceinline__ void gload_lds16(const ushort* g, ushort* l) {
    __builtin_amdgcn_global_load_lds(
        (const __attribute__((address_space(1))) void*)g,
        (__attribute__((address_space(3))) void*)l, 16, 0, 0);
}

// -------------------- h = ReLU(ids @ l1W^T + l1b), fp32 --------------------
__global__ void hyper_h(const float* __restrict__ input, const float* __restrict__ l1W,
                        const float* __restrict__ l1b, float* __restrict__ h)
{
    int b = blockIdx.x / 5;
    int o = (blockIdx.x % 5) * 256 + threadIdx.x;
    const float* ids = input + (size_t)b * 192 + 176;
    const float* w = l1W + (size_t)o * 16;
    float a = l1b[o];
#pragma unroll
    for (int i = 0; i < 16; i += 4) {
        float4 wv = *(const float4*)(w + i);
        a += ids[i] * wv.x + ids[i + 1] * wv.y + ids[i + 2] * wv.z + ids[i + 3] * wv.w;
    }
    h[(size_t)b * 1280 + o] = fmaxf(a, 0.f);
}

// -------------------- xT0[s][b] = input[b][s]  (s < 176), fp32 --------------------
__global__ void x0_t(const float* __restrict__ input, float* __restrict__ xT0)
{
    int idx = blockIdx.x * 256 + threadIdx.x;   // < 176*2048
    int s = idx >> 11, b = idx & 2047;
    xT0[idx] = input[(size_t)b * 192 + s];
}

// ---------- per-layer weight prep (FALLBACK path): wW -> bf16, plus 3 virtual B-slices ----------
// dst layout: [0..S): wW slices | [S]: bW rows | [S+1..S+2]: wb^T chunks
__global__ void cvt_layer(const float* __restrict__ wW, const float* __restrict__ wb,
                          const float* __restrict__ bW, ushort* __restrict__ dst,
                          int S, int M)
{
    int i = (blockIdx.x * 256 + threadIdx.x) * 8;       // 8 dst elements per thread
    const int nW = S * M * E_;
    union { ushort o[8]; uint4 v; } u;
    if (i < nW) {
        float4 a = *(const float4*)(wW + i);
        float4 b = *(const float4*)(wW + i + 4);
        u.o[0] = f2b(a.x); u.o[1] = f2b(a.y); u.o[2] = f2b(a.z); u.o[3] = f2b(a.w);
        u.o[4] = f2b(b.x); u.o[5] = f2b(b.y); u.o[6] = f2b(b.z); u.o[7] = f2b(b.w);
    } else {
        int rem = i - nW;                   // < 3*M*E_
        int slice = rem / (M * E_);
        int r2 = rem - slice * (M * E_);
        int m = r2 >> 7, e = r2 & 127;      // E_ = 128
        if (slice == 0) {
            const float* src = bW + (size_t)m * E_ + e;
            float4 a = *(const float4*)(src);
            float4 b = *(const float4*)(src + 4);
            u.o[0] = f2b(a.x); u.o[1] = f2b(a.y); u.o[2] = f2b(a.z); u.o[3] = f2b(a.w);
            u.o[4] = f2b(b.x); u.o[5] = f2b(b.y); u.o[6] = f2b(b.z); u.o[7] = f2b(b.w);
        } else {
#pragma unroll
            for (int jj = 0; jj < 8; ++jj) {
                int s = (slice - 1) * 128 + e + jj;
                u.o[jj] = (s < S) ? f2b(wb[(size_t)s * M + m]) : (ushort)0;
            }
        }
    }
    *(uint4*)(dst + i) = u.v;
}

// ---------- FUSED weight prep: all 5 layers in ONE dispatch (needs 111.9MB workspace) ----------
struct P5 { const float* wW[5]; const float* wb[5]; const float* bW[5]; };

__global__ void cvt_all(P5 p, ushort* __restrict__ dst)
{
    // element offsets of each layer's region in dst (ushort units)
    const size_t offE[6] = {0, 5865472, 14352384, 22839296, 31326208, 31856640};
    const int Sl[5] = {176, 256, 256, 256, 256};
    const int Ml[5] = {256, 256, 256, 256, 16};

    size_t i = ((size_t)blockIdx.x * 256 + threadIdx.x) * 8;
    if (i >= 31856640) return;
    int l = 0;
#pragma unroll
    for (int k = 1; k < 5; ++k) if (i >= offE[k]) l = k;
    const int S = Sl[l], M = Ml[l];
    const float* wW = p.wW[l];
    const float* wb = p.wb[l];
    const float* bW = p.bW[l];
    int r = (int)(i - offE[l]);
    const int nW = S * M * E_;
    union { ushort o[8]; uint4 v; } u;
    if (r < nW) {
        float4 a = *(const float4*)(wW + r);
        float4 b = *(const float4*)(wW + r + 4);
        u.o[0] = f2b(a.x); u.o[1] = f2b(a.y); u.o[2] = f2b(a.z); u.o[3] = f2b(a.w);
        u.o[4] = f2b(b.x); u.o[5] = f2b(b.y); u.o[6] = f2b(b.z); u.o[7] = f2b(b.w);
    } else {
        int rem = r - nW;                   // < 3*M*E_
        int slice = rem / (M * E_);
        int r2 = rem - slice * (M * E_);
        int m = r2 >> 7, e = r2 & 127;      // E_ = 128
        if (slice == 0) {
            const float* src = bW + (size_t)m * E_ + e;
            float4 a = *(const float4*)(src);
            float4 b = *(const float4*)(src + 4);
            u.o[0] = f2b(a.x); u.o[1] = f2b(a.y); u.o[2] = f2b(a.z); u.o[3] = f2b(a.w);
            u.o[4] = f2b(b.x); u.o[5] = f2b(b.y); u.o[6] = f2b(b.z); u.o[7] = f2b(b.w);
        } else {
#pragma unroll
            for (int jj = 0; jj < 8; ++jj) {
                int s = (slice - 1) * 128 + e + jj;
                u.o[jj] = (s < S) ? f2b(wb[(size_t)s * M + m]) : (ushort)0;
            }
        }
    }
    *(uint4*)(dst + i) = u.v;
}

// ==================== big-layer GEMM (M=256): BK=128 phases, reg-A, ring-2 ====================
// Round-4 configuration VERBATIM (proven fastest: 65.0us, VGPR 104, MfmaUtil 20%).
// BM=128, 4 waves, wave owns 32 rows x all 128 cols. A = x*h generated in registers,
// issued EARLY (before the vmcnt wait). B: ring of 2 x 32KB buffers (2 half-planes in the
// swizzled [128][64] layout). Steady-state s_waitcnt vmcnt(8) - never drains mid-loop.
// r5-r8 post-mortems: bigger blocks (8-wave) and more blocks (BM/BN splits) all regressed;
// this shape is the empirical fixed point for this problem.
__global__ __launch_bounds__(256, 2) void gemm_big(
    const ushort* __restrict__ wWb, const float* __restrict__ h,
    const float* __restrict__ xT, float* __restrict__ partial,
    int S, int iw, int ksplit, int btiles, int ntiles)
{
    __shared__ __align__(16) ushort Bs[2][2 * 128 * 64];   // [buf][plane p][row][64]
    __shared__ __align__(16) float xs[17 * 128];

    const int tid = threadIdx.x;
    const int bid = blockIdx.x;
    const int xcd = bid & 7;
    const int jj_ = bid >> 3;
    const int combo = xcd + 8 * (jj_ / btiles);
    const int bt = jj_ % btiles;
    const int nt = combo % ntiles;
    const int ks = combo / ntiles;
    const int b0 = bt * 128;
    const int m0 = nt * 128;
    const int total_s = S + 3;
    const int base = total_s / ksplit;
    const int rem = total_s - base * ksplit;
    const int s0 = ks * base + min(ks, rem);
    const int s1v = s0 + base + (ks < rem ? 1 : 0);
    const int sE = min(s1v, S);     // main loop covers [s0, sE)
    const int ns = sE - s0;         // 16..17

    const int lane = tid & 63;
    const int wave = tid >> 6;
    const int quad = lane >> 4;
    const int lr = lane & 15;
    const int wm0 = wave * 32;      // wave rows: 32; wave cols: all 128

    const int brow = lane >> 3;         // B-DMA local row (0..7)
    const int bgg = (lane & 7) ^ brow;  // global e-group for this lane's slot

    // h fragments: hreg[i][p][k2][j] = h[b0+wm0+i*16+lr][iw*128 + p*64 + k2*32 + quad*8 + j]
    float hreg[2][2][2][8];
#pragma unroll
    for (int i = 0; i < 2; ++i)
#pragma unroll
        for (int p = 0; p < 2; ++p)
#pragma unroll
            for (int k2 = 0; k2 < 2; ++k2) {
                const float* src = h + (size_t)(b0 + wm0 + i * 16 + lr) * 1280
                                     + (size_t)iw * E_ + p * 64 + k2 * 32 + quad * 8;
                float4 v0 = *(const float4*)(src);
                float4 v1 = *(const float4*)(src + 4);
                hreg[i][p][k2][0] = v0.x; hreg[i][p][k2][1] = v0.y;
                hreg[i][p][k2][2] = v0.z; hreg[i][p][k2][3] = v0.w;
                hreg[i][p][k2][4] = v1.x; hreg[i][p][k2][5] = v1.y;
                hreg[i][p][k2][6] = v1.z; hreg[i][p][k2][7] = v1.w;
            }

    // stage x-slice: xs[si][b_local]
    for (int idx = tid; idx < ns * 128; idx += 256) {
        int j = idx >> 7, bb2 = idx & 127;
        xs[idx] = xT[(size_t)(s0 + j) * NSAMP + b0 + bb2];
    }

    floatx4 acc[2][8];
#pragma unroll
    for (int i = 0; i < 2; ++i)
#pragma unroll
        for (int j = 0; j < 8; ++j)
            acc[i][j] = (floatx4){0.f, 0.f, 0.f, 0.f};

    // full-slice DMA: 8 loads/wave (2 half-planes x 4 row-groups)
    auto dmaB = [&](int s, ushort* buf) {
#pragma unroll
        for (int p = 0; p < 2; ++p)
#pragma unroll
            for (int t4 = 0; t4 < 4; ++t4) {
                int rloc = wave * 32 + t4 * 8;
                const ushort* gp = wWb + ((size_t)s * 256 + m0 + rloc + brow) * E_ + p * 64 + bgg * 8;
                gload_lds16(gp, buf + (size_t)p * 8192 + (size_t)rloc * 64 + lane * 8);
            }
    };
    // half-slice DMA (epilogue only): plane p into start of given buffer
    auto dmaBh = [&](int s, int p, ushort* buf) {
#pragma unroll
        for (int t4 = 0; t4 < 4; ++t4) {
            int rloc = wave * 32 + t4 * 8;
            const ushort* gp = wWb + ((size_t)s * 256 + m0 + rloc + brow) * E_ + p * 64 + bgg * 8;
            gload_lds16(gp, buf + (size_t)rloc * 64 + lane * 8);
        }
    };

    // prologue: drain hreg/xs, then 2 slices of DMA in flight (16 outstanding/wave)
    __builtin_amdgcn_sched_barrier(0);
    __syncthreads();
    __builtin_amdgcn_sched_barrier(0);
    dmaB(s0, &Bs[0][0]);
    if (ns > 1) dmaB(s0 + 1, &Bs[1][0]);

    for (int si = 0; si < ns; ++si) {
        // ---- A-gen for slice si, EARLY (overlaps the vmcnt wait) ----
        const float xr0 = xs[si * 128 + wm0 + lr];
        const float xr1 = xs[si * 128 + wm0 + 16 + lr];
        short8 af0[2][2], af1[2][2];   // [p][k2]
#pragma unroll
        for (int p = 0; p < 2; ++p)
#pragma unroll
            for (int k2 = 0; k2 < 2; ++k2)
#pragma unroll
                for (int j = 0; j < 8; ++j) {
                    af0[p][k2][j] = (short)f2b(xr0 * hreg[0][p][k2][j]);
                    af1[p][k2][j] = (short)f2b(xr1 * hreg[1][p][k2][j]);
                }

        if (si + 1 < ns) asm volatile("s_waitcnt vmcnt(8)" ::: "memory");
        else             asm volatile("s_waitcnt vmcnt(0)" ::: "memory");
        __builtin_amdgcn_sched_barrier(0);
        __builtin_amdgcn_s_barrier();          // slice si staged for all waves
        __builtin_amdgcn_sched_barrier(0);

        const ushort* bcur = &Bs[si & 1][0];
        __builtin_amdgcn_s_setprio(1);
#pragma unroll
        for (int kk = 0; kk < 4; ++kk) {
            const int p = kk >> 1, k2 = kk & 1;
            const int swz = ((k2 * 4 + quad) ^ (lr & 7)) * 8;
            short8 bfr[8];
#pragma unroll
            for (int j = 0; j < 8; ++j)
                bfr[j] = *(const short8*)&bcur[(size_t)p * 8192 + (size_t)(j * 16 + lr) * 64 + swz];
            const short8 a0 = (p == 0) ? ((k2 == 0) ? af0[0][0] : af0[0][1])
                                       : ((k2 == 0) ? af0[1][0] : af0[1][1]);
            const short8 a1 = (p == 0) ? ((k2 == 0) ? af1[0][0] : af1[0][1])
                                       : ((k2 == 0) ? af1[1][0] : af1[1][1]);
#pragma unroll
            for (int j = 0; j < 8; ++j) {
                acc[0][j] = __builtin_amdgcn_mfma_f32_16x16x32_bf16(a0, bfr[j], acc[0][j], 0, 0, 0);
                acc[1][j] = __builtin_amdgcn_mfma_f32_16x16x32_bf16(a1, bfr[j], acc[1][j], 0, 0, 0);
            }
        }
        __builtin_amdgcn_s_setprio(0);
        __builtin_amdgcn_sched_barrier(0);
        __builtin_amdgcn_s_barrier();          // all waves done reading Bs[si&1]
        __builtin_amdgcn_sched_barrier(0);

        if (si + 2 < ns) dmaB(s0 + si + 2, &Bs[si & 1][0]);   // ring-2 refill (WAR-safe)
    }

    // ---- virtual slices s in [S, s1v): non-pipelined (only last-ks blocks) ----
    for (int s = sE; s < s1v; ++s) {
        for (int p = 0; p < 2; ++p) {
            __syncthreads();            // full drain; previous phase's reads complete
            dmaBh(s, p, &Bs[0][0]);
            short8 af[2][2];            // [k2][i]
            if (s == S) {
#pragma unroll
                for (int k2 = 0; k2 < 2; ++k2)
#pragma unroll
                    for (int i = 0; i < 2; ++i) {
                        const float* src = h + (size_t)(b0 + wm0 + i * 16 + lr) * 1280
                                             + (size_t)(iw + 1) * E_ + p * 64 + k2 * 32 + quad * 8;
                        float4 v0 = *(const float4*)(src);
                        float4 v1 = *(const float4*)(src + 4);
                        af[k2][i][0] = (short)f2b(v0.x); af[k2][i][1] = (short)f2b(v0.y);
                        af[k2][i][2] = (short)f2b(v0.z); af[k2][i][3] = (short)f2b(v0.w);
                        af[k2][i][4] = (short)f2b(v1.x); af[k2][i][5] = (short)f2b(v1.y);
                        af[k2][i][6] = (short)f2b(v1.z); af[k2][i][7] = (short)f2b(v1.w);
                    }
            } else {
                const int jbase = (s - S - 1) * 128 + p * 64;
#pragma unroll
                for (int k2 = 0; k2 < 2; ++k2)
#pragma unroll
                    for (int i = 0; i < 2; ++i) {
                        const int b = b0 + wm0 + i * 16 + lr;
#pragma unroll
                        for (int jj = 0; jj < 8; ++jj) {
                            const int sp = jbase + k2 * 32 + quad * 8 + jj;
                            af[k2][i][jj] = (sp < S) ? (short)f2b(xT[(size_t)sp * NSAMP + b]) : (short)0;
                        }
                    }
            }
            __syncthreads();            // DMA + af loads drained
#pragma unroll
            for (int k2 = 0; k2 < 2; ++k2) {
                const int swz = ((k2 * 4 + quad) ^ (lr & 7)) * 8;
                short8 bfr[8];
#pragma unroll
                for (int j = 0; j < 8; ++j)
                    bfr[j] = *(const short8*)&Bs[0][(size_t)(j * 16 + lr) * 64 + swz];
#pragma unroll
                for (int j = 0; j < 8; ++j) {
                    acc[0][j] = __builtin_amdgcn_mfma_f32_16x16x32_bf16(af[k2][0], bfr[j], acc[0][j], 0, 0, 0);
                    acc[1][j] = __builtin_amdgcn_mfma_f32_16x16x32_bf16(af[k2][1], bfr[j], acc[1][j], 0, 0, 0);
                }
            }
        }
    }

    // C-write: C/D layout col=lane&15, row=quad*4+r
    float* dst = partial + (size_t)ks * NSAMP * 256;
#pragma unroll
    for (int i = 0; i < 2; ++i)
#pragma unroll
        for (int j = 0; j < 8; ++j)
#pragma unroll
            for (int r = 0; r < 4; ++r) {
                const int row = wm0 + i * 16 + quad * 4 + r;
                const int col = j * 16 + lr;
                dst[(size_t)(b0 + row) * 256 + m0 + col] = acc[i][j][r];
            }
}

// ==================== small-layer GEMM (M=16) — previous structure ====================
template<int BM, int BN, int WROWS, int WCOLS>
__global__ __launch_bounds__(256, 2) void gemm_k(
    const ushort* __restrict__ wWb, const float* __restrict__ h,
    const float* __restrict__ xT, float* __restrict__ partial,
    int S, int M, int iw, int ksplit, int btiles, int ntiles)
{
    constexpr int SM = BM / WROWS / 16;
    constexpr int SN = BN / WCOLS / 16;
    constexpr int ASLOTS = BM * 8 / 256;
    constexpr int LDA = 72;

    __shared__ ushort As[BM][LDA];
    __shared__ ushort Bs[BN][LDA];

    const int tid = threadIdx.x;
    const int bt = blockIdx.x % btiles;
    const int nt = (blockIdx.x / btiles) % ntiles;
    const int ks = blockIdx.x / (btiles * ntiles);
    const int b0 = bt * BM;
    const int m0 = nt * BN;
    const int total_s = S + 3;
    const int base = total_s / ksplit;
    const int rem = total_s - base * ksplit;
    const int s0 = ks * base + min(ks, rem);
    const int s1 = s0 + base + (ks < rem ? 1 : 0);

    const int lane = tid & 63;
    const int wave = tid >> 6;
    const int quad = lane >> 4;
    const int lr = lane & 15;
    const int wm0 = (wave / WCOLS) * (BM / WROWS);
    const int wn0 = (wave % WCOLS) * (BN / WCOLS);

    const int tb = tid >> 3;
    const int teg = tid & 7;

    float hreg[ASLOTS][2][8];
#pragma unroll
    for (int k2 = 0; k2 < ASLOTS; ++k2) {
        int b = tb + 32 * k2;
#pragma unroll
        for (int p = 0; p < 2; ++p) {
            const float* src = h + (size_t)(b0 + b) * 1280 + (size_t)iw * E_ + p * 64 + teg * 8;
            float4 v0 = *(const float4*)(src);
            float4 v1 = *(const float4*)(src + 4);
            hreg[k2][p][0] = v0.x; hreg[k2][p][1] = v0.y; hreg[k2][p][2] = v0.z; hreg[k2][p][3] = v0.w;
            hreg[k2][p][4] = v1.x; hreg[k2][p][5] = v1.y; hreg[k2][p][6] = v1.z; hreg[k2][p][7] = v1.w;
        }
    }

    floatx4 acc[SM][SN];
#pragma unroll
    for (int i = 0; i < SM; ++i)
#pragma unroll
        for (int j = 0; j < SN; ++j)
            acc[i][j] = (floatx4){0.f, 0.f, 0.f, 0.f};

    for (int s = s0; s < s1; ++s) {
        float xv[ASLOTS];
        if (s < S) {
#pragma unroll
            for (int k2 = 0; k2 < ASLOTS; ++k2)
                xv[k2] = xT[(size_t)s * NSAMP + b0 + tb + 32 * k2];
        }

#pragma unroll
        for (int p = 0; p < 2; ++p) {
            if (s < S) {
#pragma unroll
                for (int k2 = 0; k2 < ASLOTS; ++k2) {
                    union { ushort o[8]; uint4 v; } u;
#pragma unroll
                    for (int j = 0; j < 8; ++j) u.o[j] = f2b(xv[k2] * hreg[k2][p][j]);
                    *(uint4*)&As[tb + 32 * k2][teg * 8] = u.v;
                }
            } else if (s == S) {
#pragma unroll
                for (int k2 = 0; k2 < ASLOTS; ++k2) {
                    const float* src = h + (size_t)(b0 + tb + 32 * k2) * 1280
                                         + (size_t)(iw + 1) * E_ + p * 64 + teg * 8;
                    float4 v0 = *(const float4*)(src);
                    float4 v1 = *(const float4*)(src + 4);
                    union { ushort o[8]; uint4 v; } u;
                    u.o[0] = f2b(v0.x); u.o[1] = f2b(v0.y); u.o[2] = f2b(v0.z); u.o[3] = f2b(v0.w);
                    u.o[4] = f2b(v1.x); u.o[5] = f2b(v1.y); u.o[6] = f2b(v1.z); u.o[7] = f2b(v1.w);
                    *(uint4*)&As[tb + 32 * k2][teg * 8] = u.v;
                }
            } else {
                int j0 = (s - S - 1) * 128 + p * 64 + teg * 8;
#pragma unroll
                for (int k2 = 0; k2 < ASLOTS; ++k2) {
                    int b = b0 + tb + 32 * k2;
                    union { ushort o[8]; uint4 v; } u;
#pragma unroll
                    for (int jj = 0; jj < 8; ++jj) {
                        int sp = j0 + jj;
                        u.o[jj] = (sp < S) ? f2b(xT[(size_t)sp * NSAMP + b]) : (ushort)0;
                    }
                    *(uint4*)&As[tb + 32 * k2][teg * 8] = u.v;
                }
            }
#pragma unroll
            for (int slot = tid; slot < BN * 8; slot += 256) {
                int m = slot >> 3, eg2 = slot & 7;
                *(uint4*)&Bs[m][eg2 * 8] =
                    *(const uint4*)(wWb + ((size_t)s * M + m0 + m) * E_ + p * 64 + eg2 * 8);
            }
            __syncthreads();
#pragma unroll
            for (int kk = 0; kk < 2; ++kk) {
                short8 af[SM], bfr[SN];
#pragma unroll
                for (int i = 0; i < SM; ++i)
                    af[i] = *(const short8*)&As[wm0 + i * 16 + lr][kk * 32 + quad * 8];
#pragma unroll
                for (int j = 0; j < SN; ++j)
                    bfr[j] = *(const short8*)&Bs[wn0 + j * 16 + lr][kk * 32 + quad * 8];
#pragma unroll
                for (int i = 0; i < SM; ++i)
#pragma unroll
                    for (int j = 0; j < SN; ++j)
                        acc[i][j] = __builtin_amdgcn_mfma_f32_16x16x32_bf16(af[i], bfr[j], acc[i][j], 0, 0, 0);
            }
            __syncthreads();
        }
    }

    float* dst = partial + (size_t)ks * NSAMP * M;
#pragma unroll
    for (int i = 0; i < SM; ++i)
#pragma unroll
        for (int j = 0; j < SN; ++j)
#pragma unroll
            for (int r = 0; r < 4; ++r) {
                int row = wm0 + i * 16 + quad * 4 + r;
                int col = wn0 + j * 16 + lr;
                dst[(size_t)(b0 + row) * M + m0 + col] = acc[i][j][r];
            }
}

// -------------------- reduce partials + bb (+ReLU), emit xT fp32 for next layer --------------
__global__ void reduce_mid(const float* __restrict__ partial, const float* __restrict__ bb,
                           float* __restrict__ xTn, int KS, int relu)
{
    __shared__ float t[32][33];
    const int b0 = (blockIdx.x >> 3) * 32;
    const int m0 = (blockIdx.x & 7) * 32;
    const int mo = threadIdx.x & 31;
    const int bs0 = threadIdx.x >> 5;   // 0..7
    const float bv = bb[m0 + mo];
#pragma unroll
    for (int r = 0; r < 4; ++r) {
        const int bs = bs0 + 8 * r;
        const size_t off = (size_t)(b0 + bs) * 256 + m0 + mo;
        float a0 = 0.f, a1 = 0.f, a2 = 0.f, a3 = 0.f;
#pragma unroll
        for (int k = 0; k < 16; k += 4) {
            a0 += partial[(size_t)(k + 0) * (NSAMP * 256) + off];
            a1 += partial[(size_t)(k + 1) * (NSAMP * 256) + off];
            a2 += partial[(size_t)(k + 2) * (NSAMP * 256) + off];
            a3 += partial[(size_t)(k + 3) * (NSAMP * 256) + off];
        }
        float a = (a0 + a1) + (a2 + a3) + bv;
        if (relu) a = fmaxf(a, 0.f);
        t[bs][mo] = a;
    }
    __syncthreads();
    const int bo = threadIdx.x & 31;
    const int ms0 = threadIdx.x >> 5;
#pragma unroll
    for (int r = 0; r < 4; ++r) {
        const int ms = ms0 + 8 * r;
        xTn[(size_t)(m0 + ms) * NSAMP + b0 + bo] = t[bo][ms];
    }
}

// -------------------- final layer reduce -> d_out (fp32, ReLU) --------------------
__global__ void reduce_out(const float* __restrict__ partial, const float* __restrict__ bb,
                           float* __restrict__ out, int KS)
{
    int idx = blockIdx.x * 256 + threadIdx.x;   // < 2048*16
    float a0 = 0.f, a1 = 0.f, a2 = 0.f, a3 = 0.f;
#pragma unroll
    for (int k = 0; k < 64; k += 4) {
        a0 += partial[(size_t)(k + 0) * (NSAMP * 16) + idx];
        a1 += partial[(size_t)(k + 1) * (NSAMP * 16) + idx];
        a2 += partial[(size_t)(k + 2) * (NSAMP * 16) + idx];
        a3 += partial[(size_t)(k + 3) * (NSAMP * 16) + idx];
    }
    out[idx] = fmaxf((a0 + a1) + (a2 + a3) + bb[idx & 15], 0.f);
}

extern "C" void kernel_launch(void* const* d_in, const int* in_sizes, int n_in,
                              void* d_out, int out_size, void* d_ws, size_t ws_size,
                              hipStream_t stream)
{
    const float* input = (const float*)d_in[0];
    const float* l1W   = (const float*)d_in[1];
    const float* l1b   = (const float*)d_in[2];

    char* ws = (char*)d_ws;
    const int S_[5] = {176, 256, 256, 256, 256};
    const int M_[5] = {256, 256, 256, 256, 16};
    // per-layer element offsets in the fused weight arena
    const size_t offE[6] = {0, 5865472, 14352384, 22839296, 31326208, 31856640};

    const bool fused = ws_size >= (size_t)111947776;

    ushort* wWb5;
    float *h, *xT0, *xT1, *part;
    if (fused) {
        // layout: wWb5 63.71M | h 10.49M | xT0 2M | xT1 2M | partial 33.55M = 111.9MB
        wWb5 = (ushort*)(ws + 0);
        h    = (float*)(ws + 63713280);
        xT0  = (float*)(ws + 74199040);
        xT1  = (float*)(ws + 76296192);
        part = (float*)(ws + 78393344);
    } else {
        // legacy layout: wWb 16.98M | h 10.49M | xT0 2M | xT1 2M | partial 33.55M = 65.2MB
        wWb5 = (ushort*)(ws + 0);
        h    = (float*)(ws + 16975872);
        xT0  = (float*)(ws + 27461632);
        xT1  = (float*)(ws + 29558784);
        part = (float*)(ws + 31655936);
    }

    if (fused) {
        P5 p;
        for (int i = 0; i < 5; ++i) {
            p.wW[i] = (const float*)d_in[3 + 4 * i];
            p.wb[i] = (const float*)d_in[4 + 4 * i];
            p.bW[i] = (const float*)d_in[5 + 4 * i];
        }
        hipLaunchKernelGGL(cvt_all, dim3(15555), dim3(256), 0, stream, p, wWb5);
    }

    hipLaunchKernelGGL(hyper_h, dim3(2048 * 5), dim3(256), 0, stream, input, l1W, l1b, h);
    hipLaunchKernelGGL(x0_t, dim3(176 * 2048 / 256), dim3(256), 0, stream, input, xT0);

    float* xt[2] = {xT0, xT1};

    for (int i = 0; i < 5; ++i) {
        const float* wW = (const float*)d_in[3 + 4 * i];
        const float* wb = (const float*)d_in[4 + 4 * i];
        const float* bW = (const float*)d_in[5 + 4 * i];
        const float* bb = (const float*)d_in[6 + 4 * i];
        float* xin = xt[i & 1];

        ushort* wWbL;
        if (fused) {
            wWbL = wWb5 + offE[i];
        } else {
            wWbL = wWb5;
            int ntot = (S_[i] + 3) * M_[i] * E_;
            hipLaunchKernelGGL(cvt_layer, dim3(ntot / 2048), dim3(256), 0, stream,
                               wW, wb, bW, wWbL, S_[i], M_[i]);
        }

        if (M_[i] == 256) {
            const int btiles = 16, ntiles = 2, ksplit = 16;
            hipLaunchKernelGGL(gemm_big, dim3(btiles * ntiles * ksplit), dim3(256), 0, stream,
                               wWbL, h, xin, part, S_[i], 2 * i, ksplit, btiles, ntiles);
            hipLaunchKernelGGL(reduce_mid, dim3(512), dim3(256), 0, stream,
                               part, bb, xt[(i + 1) & 1], ksplit, (i < 3) ? 1 : 0);
        } else {
            const int btiles = 8, ntiles = 1, ksplit = 64;
            hipLaunchKernelGGL((gemm_k<256, 16, 4, 1>), dim3(btiles * ntiles * ksplit), dim3(256), 0, stream,
                               wWbL, h, xin, part, S_[i], 16, 2 * i, ksplit, btiles, ntiles);
            hipLaunchKernelGGL(reduce_out, dim3(128), dim3(256), 0, stream,
                               part, bb, (float*)d_out, ksplit);
        }
    }
}

// Round 10
// 500.214 us; speedup vs baseline: 1.9694x; 1.0189x over previous
//
#include <hip/hip_runtime.h>
#include <hip/hip_bf16.h>

#define E_ 128
#define NSAMP 2048

typedef __attribute__((ext_vector_type(8))) short short8;
typedef __attribute__((ext_vector_type(4))) float floatx4;

__device__ __forceinline__ ushort f2b(float f) {
    union { __hip_bfloat16 h; ushort u; } cv;
    cv.h = __float2bfloat16(f);
    return cv.u;
}

__device__ __forceinline__ void gload_lds16(const ushort* g, ushort* l) {
    __builtin_amdgcn_global_load_lds(
        (const __attribute__((address_space(1))) void*)g,
        (__attribute__((address_space(3))) void*)l, 16, 0, 0);
}

// -------------------- h = ReLU(ids @ l1W^T + l1b), fp32 (FALLBACK standalone) ----------
__global__ void hyper_h(const float* __restrict__ input, const float* __restrict__ l1W,
                        const float* __restrict__ l1b, float* __restrict__ h)
{
    int b = blockIdx.x / 5;
    int o = (blockIdx.x % 5) * 256 + threadIdx.x;
    const float* ids = input + (size_t)b * 192 + 176;
    const float* w = l1W + (size_t)o * 16;
    float a = l1b[o];
#pragma unroll
    for (int i = 0; i < 16; i += 4) {
        float4 wv = *(const float4*)(w + i);
        a += ids[i] * wv.x + ids[i + 1] * wv.y + ids[i + 2] * wv.z + ids[i + 3] * wv.w;
    }
    h[(size_t)b * 1280 + o] = fmaxf(a, 0.f);
}

// -------------------- xT0[s][b] = input[b][s]  (s < 176), fp32 (FALLBACK standalone) ----
__global__ void x0_t(const float* __restrict__ input, float* __restrict__ xT0)
{
    int idx = blockIdx.x * 256 + threadIdx.x;   // < 176*2048
    int s = idx >> 11, b = idx & 2047;
    xT0[idx] = input[(size_t)b * 192 + s];
}

// ---------- per-layer weight prep (FALLBACK path): wW -> bf16, plus 3 virtual B-slices ----------
__global__ void cvt_layer(const float* __restrict__ wW, const float* __restrict__ wb,
                          const float* __restrict__ bW, ushort* __restrict__ dst,
                          int S, int M)
{
    int i = (blockIdx.x * 256 + threadIdx.x) * 8;       // 8 dst elements per thread
    const int nW = S * M * E_;
    union { ushort o[8]; uint4 v; } u;
    if (i < nW) {
        float4 a = *(const float4*)(wW + i);
        float4 b = *(const float4*)(wW + i + 4);
        u.o[0] = f2b(a.x); u.o[1] = f2b(a.y); u.o[2] = f2b(a.z); u.o[3] = f2b(a.w);
        u.o[4] = f2b(b.x); u.o[5] = f2b(b.y); u.o[6] = f2b(b.z); u.o[7] = f2b(b.w);
    } else {
        int rem = i - nW;                   // < 3*M*E_
        int slice = rem / (M * E_);
        int r2 = rem - slice * (M * E_);
        int m = r2 >> 7, e = r2 & 127;      // E_ = 128
        if (slice == 0) {
            const float* src = bW + (size_t)m * E_ + e;
            float4 a = *(const float4*)(src);
            float4 b = *(const float4*)(src + 4);
            u.o[0] = f2b(a.x); u.o[1] = f2b(a.y); u.o[2] = f2b(a.z); u.o[3] = f2b(a.w);
            u.o[4] = f2b(b.x); u.o[5] = f2b(b.y); u.o[6] = f2b(b.z); u.o[7] = f2b(b.w);
        } else {
#pragma unroll
            for (int jj = 0; jj < 8; ++jj) {
                int s = (slice - 1) * 128 + e + jj;
                u.o[jj] = (s < S) ? f2b(wb[(size_t)s * M + m]) : (ushort)0;
            }
        }
    }
    *(uint4*)(dst + i) = u.v;
}

// ---------- FUSED prologue: weight cvt (all 5 layers) + hyper_h + x0_t in ONE dispatch ----------
// Block-range partition (whole blocks per job -> no divergence):
//   [0, 15555)            : weight cvt, 8 dst elems/thread
//   [15555, 15555+10240)  : hyper_h, 1 output/thread
//   [25795, 25795+1408)   : x0_t transpose
struct P5 { const float* wW[5]; const float* wb[5]; const float* bW[5]; };

__global__ void prep(P5 p, ushort* __restrict__ dst,
                     const float* __restrict__ input, const float* __restrict__ l1W,
                     const float* __restrict__ l1b, float* __restrict__ h,
                     float* __restrict__ xT0)
{
    const int blk = blockIdx.x;
    if (blk < 15555) {
        // ---- weight cvt ----
        const size_t offE[6] = {0, 5865472, 14352384, 22839296, 31326208, 31856640};
        const int Sl[5] = {176, 256, 256, 256, 256};
        const int Ml[5] = {256, 256, 256, 256, 16};
        size_t i = ((size_t)blk * 256 + threadIdx.x) * 8;
        if (i >= 31856640) return;
        int l = 0;
#pragma unroll
        for (int k = 1; k < 5; ++k) if (i >= offE[k]) l = k;
        const int S = Sl[l], M = Ml[l];
        const float* wW = p.wW[l];
        const float* wb = p.wb[l];
        const float* bW = p.bW[l];
        int r = (int)(i - offE[l]);
        const int nW = S * M * E_;
        union { ushort o[8]; uint4 v; } u;
        if (r < nW) {
            float4 a = *(const float4*)(wW + r);
            float4 b = *(const float4*)(wW + r + 4);
            u.o[0] = f2b(a.x); u.o[1] = f2b(a.y); u.o[2] = f2b(a.z); u.o[3] = f2b(a.w);
            u.o[4] = f2b(b.x); u.o[5] = f2b(b.y); u.o[6] = f2b(b.z); u.o[7] = f2b(b.w);
        } else {
            int rem = r - nW;                   // < 3*M*E_
            int slice = rem / (M * E_);
            int r2 = rem - slice * (M * E_);
            int m = r2 >> 7, e = r2 & 127;      // E_ = 128
            if (slice == 0) {
                const float* src = bW + (size_t)m * E_ + e;
                float4 a = *(const float4*)(src);
                float4 b = *(const float4*)(src + 4);
                u.o[0] = f2b(a.x); u.o[1] = f2b(a.y); u.o[2] = f2b(a.z); u.o[3] = f2b(a.w);
                u.o[4] = f2b(b.x); u.o[5] = f2b(b.y); u.o[6] = f2b(b.z); u.o[7] = f2b(b.w);
            } else {
#pragma unroll
                for (int jj = 0; jj < 8; ++jj) {
                    int s = (slice - 1) * 128 + e + jj;
                    u.o[jj] = (s < S) ? f2b(wb[(size_t)s * M + m]) : (ushort)0;
                }
            }
        }
        *(uint4*)(dst + i) = u.v;
    } else if (blk < 15555 + 10240) {
        // ---- hyper_h ----
        const int b2 = blk - 15555;
        const int b = b2 / 5;
        const int o = (b2 % 5) * 256 + threadIdx.x;
        const float* ids = input + (size_t)b * 192 + 176;
        const float* w = l1W + (size_t)o * 16;
        float a = l1b[o];
#pragma unroll
        for (int i = 0; i < 16; i += 4) {
            float4 wv = *(const float4*)(w + i);
            a += ids[i] * wv.x + ids[i + 1] * wv.y + ids[i + 2] * wv.z + ids[i + 3] * wv.w;
        }
        h[(size_t)b * 1280 + o] = fmaxf(a, 0.f);
    } else {
        // ---- x0_t ----
        const int idx = (blk - 25795) * 256 + threadIdx.x;   // < 176*2048
        const int s = idx >> 11, b = idx & 2047;
        xT0[idx] = input[(size_t)b * 192 + s];
    }
}

// ==================== big-layer GEMM (M=256): BK=128 phases, reg-A, ring-2 ====================
// Round-4/9 configuration VERBATIM (proven fixed point: 65.0us, VGPR 104, MfmaUtil 20%).
// r5-r8 post-mortems: all occupancy/form-factor variants regressed; do not touch.
__global__ __launch_bounds__(256, 2) void gemm_big(
    const ushort* __restrict__ wWb, const float* __restrict__ h,
    const float* __restrict__ xT, float* __restrict__ partial,
    int S, int iw, int ksplit, int btiles, int ntiles)
{
    __shared__ __align__(16) ushort Bs[2][2 * 128 * 64];   // [buf][plane p][row][64]
    __shared__ __align__(16) float xs[17 * 128];

    const int tid = threadIdx.x;
    const int bid = blockIdx.x;
    const int xcd = bid & 7;
    const int jj_ = bid >> 3;
    const int combo = xcd + 8 * (jj_ / btiles);
    const int bt = jj_ % btiles;
    const int nt = combo % ntiles;
    const int ks = combo / ntiles;
    const int b0 = bt * 128;
    const int m0 = nt * 128;
    const int total_s = S + 3;
    const int base = total_s / ksplit;
    const int rem = total_s - base * ksplit;
    const int s0 = ks * base + min(ks, rem);
    const int s1v = s0 + base + (ks < rem ? 1 : 0);
    const int sE = min(s1v, S);     // main loop covers [s0, sE)
    const int ns = sE - s0;         // 16..17

    const int lane = tid & 63;
    const int wave = tid >> 6;
    const int quad = lane >> 4;
    const int lr = lane & 15;
    const int wm0 = wave * 32;      // wave rows: 32; wave cols: all 128

    const int brow = lane >> 3;         // B-DMA local row (0..7)
    const int bgg = (lane & 7) ^ brow;  // global e-group for this lane's slot

    // h fragments: hreg[i][p][k2][j] = h[b0+wm0+i*16+lr][iw*128 + p*64 + k2*32 + quad*8 + j]
    float hreg[2][2][2][8];
#pragma unroll
    for (int i = 0; i < 2; ++i)
#pragma unroll
        for (int p = 0; p < 2; ++p)
#pragma unroll
            for (int k2 = 0; k2 < 2; ++k2) {
                const float* src = h + (size_t)(b0 + wm0 + i * 16 + lr) * 1280
                                     + (size_t)iw * E_ + p * 64 + k2 * 32 + quad * 8;
                float4 v0 = *(const float4*)(src);
                float4 v1 = *(const float4*)(src + 4);
                hreg[i][p][k2][0] = v0.x; hreg[i][p][k2][1] = v0.y;
                hreg[i][p][k2][2] = v0.z; hreg[i][p][k2][3] = v0.w;
                hreg[i][p][k2][4] = v1.x; hreg[i][p][k2][5] = v1.y;
                hreg[i][p][k2][6] = v1.z; hreg[i][p][k2][7] = v1.w;
            }

    // stage x-slice: xs[si][b_local]
    for (int idx = tid; idx < ns * 128; idx += 256) {
        int j = idx >> 7, bb2 = idx & 127;
        xs[idx] = xT[(size_t)(s0 + j) * NSAMP + b0 + bb2];
    }

    floatx4 acc[2][8];
#pragma unroll
    for (int i = 0; i < 2; ++i)
#pragma unroll
        for (int j = 0; j < 8; ++j)
            acc[i][j] = (floatx4){0.f, 0.f, 0.f, 0.f};

    // full-slice DMA: 8 loads/wave (2 half-planes x 4 row-groups)
    auto dmaB = [&](int s, ushort* buf) {
#pragma unroll
        for (int p = 0; p < 2; ++p)
#pragma unroll
            for (int t4 = 0; t4 < 4; ++t4) {
                int rloc = wave * 32 + t4 * 8;
                const ushort* gp = wWb + ((size_t)s * 256 + m0 + rloc + brow) * E_ + p * 64 + bgg * 8;
                gload_lds16(gp, buf + (size_t)p * 8192 + (size_t)rloc * 64 + lane * 8);
            }
    };
    // half-slice DMA (epilogue only): plane p into start of given buffer
    auto dmaBh = [&](int s, int p, ushort* buf) {
#pragma unroll
        for (int t4 = 0; t4 < 4; ++t4) {
            int rloc = wave * 32 + t4 * 8;
            const ushort* gp = wWb + ((size_t)s * 256 + m0 + rloc + brow) * E_ + p * 64 + bgg * 8;
            gload_lds16(gp, buf + (size_t)rloc * 64 + lane * 8);
        }
    };

    // prologue: drain hreg/xs, then 2 slices of DMA in flight (16 outstanding/wave)
    __builtin_amdgcn_sched_barrier(0);
    __syncthreads();
    __builtin_amdgcn_sched_barrier(0);
    dmaB(s0, &Bs[0][0]);
    if (ns > 1) dmaB(s0 + 1, &Bs[1][0]);

    for (int si = 0; si < ns; ++si) {
        // ---- A-gen for slice si, EARLY (overlaps the vmcnt wait) ----
        const float xr0 = xs[si * 128 + wm0 + lr];
        const float xr1 = xs[si * 128 + wm0 + 16 + lr];
        short8 af0[2][2], af1[2][2];   // [p][k2]
#pragma unroll
        for (int p = 0; p < 2; ++p)
#pragma unroll
            for (int k2 = 0; k2 < 2; ++k2)
#pragma unroll
                for (int j = 0; j < 8; ++j) {
                    af0[p][k2][j] = (short)f2b(xr0 * hreg[0][p][k2][j]);
                    af1[p][k2][j] = (short)f2b(xr1 * hreg[1][p][k2][j]);
                }

        if (si + 1 < ns) asm volatile("s_waitcnt vmcnt(8)" ::: "memory");
        else             asm volatile("s_waitcnt vmcnt(0)" ::: "memory");
        __builtin_amdgcn_sched_barrier(0);
        __builtin_amdgcn_s_barrier();          // slice si staged for all waves
        __builtin_amdgcn_sched_barrier(0);

        const ushort* bcur = &Bs[si & 1][0];
        __builtin_amdgcn_s_setprio(1);
#pragma unroll
        for (int kk = 0; kk < 4; ++kk) {
            const int p = kk >> 1, k2 = kk & 1;
            const int swz = ((k2 * 4 + quad) ^ (lr & 7)) * 8;
            short8 bfr[8];
#pragma unroll
            for (int j = 0; j < 8; ++j)
                bfr[j] = *(const short8*)&bcur[(size_t)p * 8192 + (size_t)(j * 16 + lr) * 64 + swz];
            const short8 a0 = (p == 0) ? ((k2 == 0) ? af0[0][0] : af0[0][1])
                                       : ((k2 == 0) ? af0[1][0] : af0[1][1]);
            const short8 a1 = (p == 0) ? ((k2 == 0) ? af1[0][0] : af1[0][1])
                                       : ((k2 == 0) ? af1[1][0] : af1[1][1]);
#pragma unroll
            for (int j = 0; j < 8; ++j) {
                acc[0][j] = __builtin_amdgcn_mfma_f32_16x16x32_bf16(a0, bfr[j], acc[0][j], 0, 0, 0);
                acc[1][j] = __builtin_amdgcn_mfma_f32_16x16x32_bf16(a1, bfr[j], acc[1][j], 0, 0, 0);
            }
        }
        __builtin_amdgcn_s_setprio(0);
        __builtin_amdgcn_sched_barrier(0);
        __builtin_amdgcn_s_barrier();          // all waves done reading Bs[si&1]
        __builtin_amdgcn_sched_barrier(0);

        if (si + 2 < ns) dmaB(s0 + si + 2, &Bs[si & 1][0]);   // ring-2 refill (WAR-safe)
    }

    // ---- virtual slices s in [S, s1v): non-pipelined (only last-ks blocks) ----
    for (int s = sE; s < s1v; ++s) {
        for (int p = 0; p < 2; ++p) {
            __syncthreads();            // full drain; previous phase's reads complete
            dmaBh(s, p, &Bs[0][0]);
            short8 af[2][2];            // [k2][i]
            if (s == S) {
#pragma unroll
                for (int k2 = 0; k2 < 2; ++k2)
#pragma unroll
                    for (int i = 0; i < 2; ++i) {
                        const float* src = h + (size_t)(b0 + wm0 + i * 16 + lr) * 1280
                                             + (size_t)(iw + 1) * E_ + p * 64 + k2 * 32 + quad * 8;
                        float4 v0 = *(const float4*)(src);
                        float4 v1 = *(const float4*)(src + 4);
                        af[k2][i][0] = (short)f2b(v0.x); af[k2][i][1] = (short)f2b(v0.y);
                        af[k2][i][2] = (short)f2b(v0.z); af[k2][i][3] = (short)f2b(v0.w);
                        af[k2][i][4] = (short)f2b(v1.x); af[k2][i][5] = (short)f2b(v1.y);
                        af[k2][i][6] = (short)f2b(v1.z); af[k2][i][7] = (short)f2b(v1.w);
                    }
            } else {
                const int jbase = (s - S - 1) * 128 + p * 64;
#pragma unroll
                for (int k2 = 0; k2 < 2; ++k2)
#pragma unroll
                    for (int i = 0; i < 2; ++i) {
                        const int b = b0 + wm0 + i * 16 + lr;
#pragma unroll
                        for (int jj = 0; jj < 8; ++jj) {
                            const int sp = jbase + k2 * 32 + quad * 8 + jj;
                            af[k2][i][jj] = (sp < S) ? (short)f2b(xT[(size_t)sp * NSAMP + b]) : (short)0;
                        }
                    }
            }
            __syncthreads();            // DMA + af loads drained
#pragma unroll
            for (int k2 = 0; k2 < 2; ++k2) {
                const int swz = ((k2 * 4 + quad) ^ (lr & 7)) * 8;
                short8 bfr[8];
#pragma unroll
                for (int j = 0; j < 8; ++j)
                    bfr[j] = *(const short8*)&Bs[0][(size_t)(j * 16 + lr) * 64 + swz];
#pragma unroll
                for (int j = 0; j < 8; ++j) {
                    acc[0][j] = __builtin_amdgcn_mfma_f32_16x16x32_bf16(af[k2][0], bfr[j], acc[0][j], 0, 0, 0);
                    acc[1][j] = __builtin_amdgcn_mfma_f32_16x16x32_bf16(af[k2][1], bfr[j], acc[1][j], 0, 0, 0);
                }
            }
        }
    }

    // C-write: C/D layout col=lane&15, row=quad*4+r
    float* dst = partial + (size_t)ks * NSAMP * 256;
#pragma unroll
    for (int i = 0; i < 2; ++i)
#pragma unroll
        for (int j = 0; j < 8; ++j)
#pragma unroll
            for (int r = 0; r < 4; ++r) {
                const int row = wm0 + i * 16 + quad * 4 + r;
                const int col = j * 16 + lr;
                dst[(size_t)(b0 + row) * 256 + m0 + col] = acc[i][j][r];
            }
}

// ==================== small-layer GEMM (M=16) — previous structure ====================
template<int BM, int BN, int WROWS, int WCOLS>
__global__ __launch_bounds__(256, 2) void gemm_k(
    const ushort* __restrict__ wWb, const float* __restrict__ h,
    const float* __restrict__ xT, float* __restrict__ partial,
    int S, int M, int iw, int ksplit, int btiles, int ntiles)
{
    constexpr int SM = BM / WROWS / 16;
    constexpr int SN = BN / WCOLS / 16;
    constexpr int ASLOTS = BM * 8 / 256;
    constexpr int LDA = 72;

    __shared__ ushort As[BM][LDA];
    __shared__ ushort Bs[BN][LDA];

    const int tid = threadIdx.x;
    const int bt = blockIdx.x % btiles;
    const int nt = (blockIdx.x / btiles) % ntiles;
    const int ks = blockIdx.x / (btiles * ntiles);
    const int b0 = bt * BM;
    const int m0 = nt * BN;
    const int total_s = S + 3;
    const int base = total_s / ksplit;
    const int rem = total_s - base * ksplit;
    const int s0 = ks * base + min(ks, rem);
    const int s1 = s0 + base + (ks < rem ? 1 : 0);

    const int lane = tid & 63;
    const int wave = tid >> 6;
    const int quad = lane >> 4;
    const int lr = lane & 15;
    const int wm0 = (wave / WCOLS) * (BM / WROWS);
    const int wn0 = (wave % WCOLS) * (BN / WCOLS);

    const int tb = tid >> 3;
    const int teg = tid & 7;

    float hreg[ASLOTS][2][8];
#pragma unroll
    for (int k2 = 0; k2 < ASLOTS; ++k2) {
        int b = tb + 32 * k2;
#pragma unroll
        for (int p = 0; p < 2; ++p) {
            const float* src = h + (size_t)(b0 + b) * 1280 + (size_t)iw * E_ + p * 64 + teg * 8;
            float4 v0 = *(const float4*)(src);
            float4 v1 = *(const float4*)(src + 4);
            hreg[k2][p][0] = v0.x; hreg[k2][p][1] = v0.y; hreg[k2][p][2] = v0.z; hreg[k2][p][3] = v0.w;
            hreg[k2][p][4] = v1.x; hreg[k2][p][5] = v1.y; hreg[k2][p][6] = v1.z; hreg[k2][p][7] = v1.w;
        }
    }

    floatx4 acc[SM][SN];
#pragma unroll
    for (int i = 0; i < SM; ++i)
#pragma unroll
        for (int j = 0; j < SN; ++j)
            acc[i][j] = (floatx4){0.f, 0.f, 0.f, 0.f};

    for (int s = s0; s < s1; ++s) {
        float xv[ASLOTS];
        if (s < S) {
#pragma unroll
            for (int k2 = 0; k2 < ASLOTS; ++k2)
                xv[k2] = xT[(size_t)s * NSAMP + b0 + tb + 32 * k2];
        }

#pragma unroll
        for (int p = 0; p < 2; ++p) {
            if (s < S) {
#pragma unroll
                for (int k2 = 0; k2 < ASLOTS; ++k2) {
                    union { ushort o[8]; uint4 v; } u;
#pragma unroll
                    for (int j = 0; j < 8; ++j) u.o[j] = f2b(xv[k2] * hreg[k2][p][j]);
                    *(uint4*)&As[tb + 32 * k2][teg * 8] = u.v;
                }
            } else if (s == S) {
#pragma unroll
                for (int k2 = 0; k2 < ASLOTS; ++k2) {
                    const float* src = h + (size_t)(b0 + tb + 32 * k2) * 1280
                                         + (size_t)(iw + 1) * E_ + p * 64 + teg * 8;
                    float4 v0 = *(const float4*)(src);
                    float4 v1 = *(const float4*)(src + 4);
                    union { ushort o[8]; uint4 v; } u;
                    u.o[0] = f2b(v0.x); u.o[1] = f2b(v0.y); u.o[2] = f2b(v0.z); u.o[3] = f2b(v0.w);
                    u.o[4] = f2b(v1.x); u.o[5] = f2b(v1.y); u.o[6] = f2b(v1.z); u.o[7] = f2b(v1.w);
                    *(uint4*)&As[tb + 32 * k2][teg * 8] = u.v;
                }
            } else {
                int j0 = (s - S - 1) * 128 + p * 64 + teg * 8;
#pragma unroll
                for (int k2 = 0; k2 < ASLOTS; ++k2) {
                    int b = b0 + tb + 32 * k2;
                    union { ushort o[8]; uint4 v; } u;
#pragma unroll
                    for (int jj = 0; jj < 8; ++jj) {
                        int sp = j0 + jj;
                        u.o[jj] = (sp < S) ? f2b(xT[(size_t)sp * NSAMP + b]) : (ushort)0;
                    }
                    *(uint4*)&As[tb + 32 * k2][teg * 8] = u.v;
                }
            }
#pragma unroll
            for (int slot = tid; slot < BN * 8; slot += 256) {
                int m = slot >> 3, eg2 = slot & 7;
                *(uint4*)&Bs[m][eg2 * 8] =
                    *(const uint4*)(wWb + ((size_t)s * M + m0 + m) * E_ + p * 64 + eg2 * 8);
            }
            __syncthreads();
#pragma unroll
            for (int kk = 0; kk < 2; ++kk) {
                short8 af[SM], bfr[SN];
#pragma unroll
                for (int i = 0; i < SM; ++i)
                    af[i] = *(const short8*)&As[wm0 + i * 16 + lr][kk * 32 + quad * 8];
#pragma unroll
                for (int j = 0; j < SN; ++j)
                    bfr[j] = *(const short8*)&Bs[wn0 + j * 16 + lr][kk * 32 + quad * 8];
#pragma unroll
                for (int i = 0; i < SM; ++i)
#pragma unroll
                    for (int j = 0; j < SN; ++j)
                        acc[i][j] = __builtin_amdgcn_mfma_f32_16x16x32_bf16(af[i], bfr[j], acc[i][j], 0, 0, 0);
            }
            __syncthreads();
        }
    }

    float* dst = partial + (size_t)ks * NSAMP * M;
#pragma unroll
    for (int i = 0; i < SM; ++i)
#pragma unroll
        for (int j = 0; j < SN; ++j)
#pragma unroll
            for (int r = 0; r < 4; ++r) {
                int row = wm0 + i * 16 + quad * 4 + r;
                int col = wn0 + j * 16 + lr;
                dst[(size_t)(b0 + row) * M + m0 + col] = acc[i][j][r];
            }
}

// -------------------- reduce partials + bb (+ReLU), emit xT fp32 for next layer --------------
__global__ void reduce_mid(const float* __restrict__ partial, const float* __restrict__ bb,
                           float* __restrict__ xTn, int KS, int relu)
{
    __shared__ float t[32][33];
    const int b0 = (blockIdx.x >> 3) * 32;
    const int m0 = (blockIdx.x & 7) * 32;
    const int mo = threadIdx.x & 31;
    const int bs0 = threadIdx.x >> 5;   // 0..7
    const float bv = bb[m0 + mo];
#pragma unroll
    for (int r = 0; r < 4; ++r) {
        const int bs = bs0 + 8 * r;
        const size_t off = (size_t)(b0 + bs) * 256 + m0 + mo;
        float a0 = 0.f, a1 = 0.f, a2 = 0.f, a3 = 0.f;
#pragma unroll
        for (int k = 0; k < 16; k += 4) {
            a0 += partial[(size_t)(k + 0) * (NSAMP * 256) + off];
            a1 += partial[(size_t)(k + 1) * (NSAMP * 256) + off];
            a2 += partial[(size_t)(k + 2) * (NSAMP * 256) + off];
            a3 += partial[(size_t)(k + 3) * (NSAMP * 256) + off];
        }
        float a = (a0 + a1) + (a2 + a3) + bv;
        if (relu) a = fmaxf(a, 0.f);
        t[bs][mo] = a;
    }
    __syncthreads();
    const int bo = threadIdx.x & 31;
    const int ms0 = threadIdx.x >> 5;
#pragma unroll
    for (int r = 0; r < 4; ++r) {
        const int ms = ms0 + 8 * r;
        xTn[(size_t)(m0 + ms) * NSAMP + b0 + bo] = t[bo][ms];
    }
}

// -------------------- final layer reduce -> d_out (fp32, ReLU) --------------------
__global__ void reduce_out(const float* __restrict__ partial, const float* __restrict__ bb,
                           float* __restrict__ out, int KS)
{
    int idx = blockIdx.x * 256 + threadIdx.x;   // < 2048*16
    float a0 = 0.f, a1 = 0.f, a2 = 0.f, a3 = 0.f;
#pragma unroll
    for (int k = 0; k < 64; k += 4) {
        a0 += partial[(size_t)(k + 0) * (NSAMP * 16) + idx];
        a1 += partial[(size_t)(k + 1) * (NSAMP * 16) + idx];
        a2 += partial[(size_t)(k + 2) * (NSAMP * 16) + idx];
        a3 += partial[(size_t)(k + 3) * (NSAMP * 16) + idx];
    }
    out[idx] = fmaxf((a0 + a1) + (a2 + a3) + bb[idx & 15], 0.f);
}

extern "C" void kernel_launch(void* const* d_in, const int* in_sizes, int n_in,
                              void* d_out, int out_size, void* d_ws, size_t ws_size,
                              hipStream_t stream)
{
    const float* input = (const float*)d_in[0];
    const float* l1W   = (const float*)d_in[1];
    const float* l1b   = (const float*)d_in[2];

    char* ws = (char*)d_ws;
    const int S_[5] = {176, 256, 256, 256, 256};
    const int M_[5] = {256, 256, 256, 256, 16};
    // per-layer element offsets in the fused weight arena
    const size_t offE[6] = {0, 5865472, 14352384, 22839296, 31326208, 31856640};

    const bool fused = ws_size >= (size_t)111947776;

    ushort* wWb5;
    float *h, *xT0, *xT1, *part;
    if (fused) {
        // layout: wWb5 63.71M | h 10.49M | xT0 2M | xT1 2M | partial 33.55M = 111.9MB
        wWb5 = (ushort*)(ws + 0);
        h    = (float*)(ws + 63713280);
        xT0  = (float*)(ws + 74199040);
        xT1  = (float*)(ws + 76296192);
        part = (float*)(ws + 78393344);
    } else {
        // legacy layout: wWb 16.98M | h 10.49M | xT0 2M | xT1 2M | partial 33.55M = 65.2MB
        wWb5 = (ushort*)(ws + 0);
        h    = (float*)(ws + 16975872);
        xT0  = (float*)(ws + 27461632);
        xT1  = (float*)(ws + 29558784);
        part = (float*)(ws + 31655936);
    }

    if (fused) {
        P5 p;
        for (int i = 0; i < 5; ++i) {
            p.wW[i] = (const float*)d_in[3 + 4 * i];
            p.wb[i] = (const float*)d_in[4 + 4 * i];
            p.bW[i] = (const float*)d_in[5 + 4 * i];
        }
        // single fused prologue: weight cvt + hyper_h + x0_t (15555 + 10240 + 1408 blocks)
        hipLaunchKernelGGL(prep, dim3(27203), dim3(256), 0, stream,
                           p, wWb5, input, l1W, l1b, h, xT0);
    } else {
        hipLaunchKernelGGL(hyper_h, dim3(2048 * 5), dim3(256), 0, stream, input, l1W, l1b, h);
        hipLaunchKernelGGL(x0_t, dim3(176 * 2048 / 256), dim3(256), 0, stream, input, xT0);
    }

    float* xt[2] = {xT0, xT1};

    for (int i = 0; i < 5; ++i) {
        const float* wW = (const float*)d_in[3 + 4 * i];
        const float* wb = (const float*)d_in[4 + 4 * i];
        const float* bW = (const float*)d_in[5 + 4 * i];
        const float* bb = (const float*)d_in[6 + 4 * i];
        float* xin = xt[i & 1];

        ushort* wWbL;
        if (fused) {
            wWbL = wWb5 + offE[i];
        } else {
            wWbL = wWb5;
            int ntot = (S_[i] + 3) * M_[i] * E_;
            hipLaunchKernelGGL(cvt_layer, dim3(ntot / 2048), dim3(256), 0, stream,
                               wW, wb, bW, wWbL, S_[i], M_[i]);
        }

        if (M_[i] == 256) {
            const int btiles = 16, ntiles = 2, ksplit = 16;
            hipLaunchKernelGGL(gemm_big, dim3(btiles * ntiles * ksplit), dim3(256), 0, stream,
                               wWbL, h, xin, part, S_[i], 2 * i, ksplit, btiles, ntiles);
            hipLaunchKernelGGL(reduce_mid, dim3(512), dim3(256), 0, stream,
                               part, bb, xt[(i + 1) & 1], ksplit, (i < 3) ? 1 : 0);
        } else {
            const int btiles = 8, ntiles = 1, ksplit = 64;
            hipLaunchKernelGGL((gemm_k<256, 16, 4, 1>), dim3(btiles * ntiles * ksplit), dim3(256), 0, stream,
                               wWbL, h, xin, part, S_[i], 16, 2 * i, ksplit, btiles, ntiles);
            hipLaunchKernelGGL(reduce_out, dim3(128), dim3(256), 0, stream,
                               part, bb, (float*)d_out, ksplit);
        }
    }
}